// Round 12
// baseline (296.809 us; speedup 1.0000x reference)
//
#include <hip/hip_runtime.h>
#include <cmath>
#include <complex>
#include <algorithm>

#ifndef M_PI
#define M_PI 3.14159265358979323846
#endif

typedef _Float16 f16x8 __attribute__((ext_vector_type(8)));
typedef _Float16 f16x4 __attribute__((ext_vector_type(4)));
typedef float f32x4 __attribute__((ext_vector_type(4)));

// ---------------- coefficient structs (passed by value as kernel args) ---------
struct FiltArg {
  double b0[3], b1[3], b2[3], a1[3], a2[3];
  double zi0[3], zi1[3];
  double A32[36];              // (state-transition matrix)^32, 6x6 row-major
};
struct CorArg { double CA[32 * 6]; };  // CA[i][j] = output at step i from unit state e_j

// ---------------- host-side filter design (exact replica of reference) --------
static void design_sos(FiltArg& sa) {
  const int order = 6;
  const double wn = 0.5 / 50.0;
  const double fs = 2.0;
  double warped = 2.0 * fs * std::tan(M_PI * wn / fs);
  std::complex<double> p[6];
  for (int i = 0; i < order; i++) {
    int m = -order + 1 + 2 * i;                      // -5,-3,-1,1,3,5
    p[i] = -std::exp(std::complex<double>(0.0, M_PI * m / (2.0 * order)));
  }
  std::complex<double> prod1(1, 0);
  for (int i = 0; i < 6; i++) prod1 *= -p[i];
  double k = (1.0 / prod1).real();
  for (int i = 0; i < 6; i++) p[i] = warped / p[i];
  const double fs2 = 2.0 * fs;
  std::complex<double> num(1, 0), den(1, 0);
  for (int i = 0; i < 6; i++) { num *= fs2; den *= (fs2 - p[i]); }
  k *= (num / den).real();
  for (int i = 0; i < 6; i++) p[i] = (fs2 + p[i]) / (fs2 - p[i]);
  std::complex<double> pp[3]; int n = 0;
  for (int i = 0; i < 6; i++) if (p[i].imag() > 0) pp[n++] = p[i];
  std::stable_sort(pp, pp + 3,
    [](const std::complex<double>& A, const std::complex<double>& B) {
      return std::fabs(std::abs(A) - 1.0) > std::fabs(std::abs(B) - 1.0);
    });
  double sos[3][6];
  for (int s = 0; s < 3; s++) {
    double g = (s == 0) ? k : 1.0;
    sos[s][0] = g; sos[s][1] = -2.0 * g; sos[s][2] = g;
    sos[s][3] = 1.0; sos[s][4] = -2.0 * pp[s].real(); sos[s][5] = std::norm(pp[s]);
  }
  double scale = 1.0;
  for (int s = 0; s < 3; s++) {
    double b0 = sos[s][0], b1 = sos[s][1], b2 = sos[s][2];
    double a1 = sos[s][4], a2 = sos[s][5];
    double det = 1.0 + a1 + a2;                      // det of [[1+a1,-1],[a2,1]]
    double r0 = b1 - a1 * b0, r1 = b2 - a2 * b0;
    double z0 = (r0 + r1) / det;
    double z1 = ((1.0 + a1) * r1 - a2 * r0) / det;
    sa.b0[s] = b0; sa.b1[s] = b1; sa.b2[s] = b2; sa.a1[s] = a1; sa.a2[s] = a2;
    sa.zi0[s] = scale * z0; sa.zi1[s] = scale * z1;
    scale *= (b0 + b1 + b2) / (1.0 + a1 + a2);
  }
}

static double host_step(const FiltArg& c, double z[6], double v) {
  for (int s = 0; s < 3; s++) {
    double y = c.b0[s] * v + z[2 * s];
    z[2 * s]     = c.b1[s] * v - c.a1[s] * y + z[2 * s + 1];
    z[2 * s + 1] = c.b2[s] * v - c.a2[s] * y;
    v = y;
  }
  return v;
}

static void build_filt(FiltArg& c, CorArg& co) {
  design_sos(c);
  double A[36];
  for (int j = 0; j < 6; j++) {
    double z[6] = {0, 0, 0, 0, 0, 0};
    z[j] = 1.0;
    host_step(c, z, 0.0);
    for (int i = 0; i < 6; i++) A[i * 6 + j] = z[i];
  }
  double M[36], T[36];
  for (int i = 0; i < 36; i++) M[i] = A[i];
  for (int sq = 0; sq < 5; sq++) {
    for (int i = 0; i < 6; i++)
      for (int j = 0; j < 6; j++) {
        double s = 0.0;
        for (int kk = 0; kk < 6; kk++) s += M[i * 6 + kk] * M[kk * 6 + j];
        T[i * 6 + j] = s;
      }
    for (int i = 0; i < 36; i++) M[i] = T[i];
  }
  for (int i = 0; i < 36; i++) c.A32[i] = M[i];
  // CA[i][j]: output at chunk-step i starting from unit state e_j, zero input
  for (int j = 0; j < 6; j++) {
    double z[6] = {0, 0, 0, 0, 0, 0};
    z[j] = 1.0;
    for (int i = 0; i < 32; i++) co.CA[i * 6 + j] = host_step(c, z, 0.0);
  }
}

// ---------------- device helpers ----------------
__device__ inline double waveReduceSum(double v) {
  #pragma unroll
  for (int off = 32; off > 0; off >>= 1) v += __shfl_down(v, off, 64);
  return v;
}

__device__ inline double dbessel_i0(double x) {
  double s = 1.0, t = 1.0;
  for (int k = 1; k < 64; k++) {
    double u = x / (2.0 * k);
    t *= u * u; s += t;
    if (t < 1e-18 * s) break;
  }
  return s;
}

// ---------------- kernel 1: chansel + demean, PE table, FIR taps, out-zero ----
// Blocks [0,500): channel select + demean. Blocks [500,580): PE table (f64
// trig); block 579 also zeros d_out. Block 580: FIR tap design on device
// (f64 sinc x Kaiser, mirrors host design_fir) -> hbuf[526] for the fused
// filtfilt+resample kernel (taps can't ride in kernarg: FiltArg+CorArg
// already ~2KB).
__global__ __launch_bounds__(256) void k_chansel_pe(const float* __restrict__ x,
                                                    float* __restrict__ xs,
                                                    float* __restrict__ pe,
                                                    float* __restrict__ hbuf,
                                                    float* __restrict__ out) {
  int gid = blockIdx.x;
  int tid = threadIdx.x;
  if (gid < 500) {
    int idx = gid * 256 + tid;
    int b = idx / 2000, t = idx % 2000;
    const int ch[10] = {126, 125, 48, 112, 67, 93, 10, 61, 39, 108};
    const float* xb = x + (size_t)b * 128 * 2000;
    float v[10]; float s = 0.f;
    #pragma unroll
    for (int c = 0; c < 10; c++) { v[c] = xb[ch[c] * 2000 + t]; s += v[c]; }
    s *= 0.1f;
    #pragma unroll
    for (int c = 0; c < 10; c++) xs[((size_t)b * 10 + c) * 2000 + t] = v[c] - s;
  } else if (gid < 580) {
    int i = (gid - 500) * 256 + tid;            // [0, 20480)
    int t = i >> 4, d = i & 15, j = d >> 1;
    double div = exp(-((double)(2 * j)) * 0.5756462732485114); // ln(10000)/16
    double a = (double)t * div;
    pe[i] = (float)((d & 1) ? cos(a) : sin(a));
    if (gid == 579 && tid < 64) out[tid] = 0.f;
  } else {
    // FIR design: h[nn] = fc*sinc(fc*m)*kaiser(501,5)[nn]; normalize; *UP
    __shared__ double hd[501];
    __shared__ double red[4];
    const double fc = 1.0 / 25.0;
    double denom = dbessel_i0(5.0);
    for (int nn = tid; nn < 501; nn += 256) {
      double m = nn - 250.0;
      double xx = fc * m;
      double snc = (nn == 250) ? 1.0 : sin(M_PI * xx) / (M_PI * xx);
      double r = (2.0 * nn) / 500.0 - 1.0;
      double w = dbessel_i0(5.0 * sqrt(fmax(0.0, 1.0 - r * r))) / denom;
      hd[nn] = fc * snc * w;
    }
    __syncthreads();
    double s = 0.0;
    for (int nn = tid; nn < 501; nn += 256) s += hd[nn];
    s = waveReduceSum(s);
    int wid = tid >> 6, lane = tid & 63;
    if (lane == 0) red[wid] = s;
    __syncthreads();
    double sum = red[0] + red[1] + red[2] + red[3];
    for (int i = tid; i < 526; i += 256)
      hbuf[i] = (i < 25) ? 0.f : (float)(hd[i - 25] / sum * 16.0);
  }
}

// ---------------- kernel 2: filtfilt + resample + tanh + normalize (fused) ----
// One block = one wave per row. Filtfilt: round-9 measured-best structure
// (register y_zero, CA correction, 6-lane shfl scan). The filtered row is
// then written into the dead xr LDS buffer and the 33-tap polyphase FIR +
// tanh + single-wave normalize run in-block -- no HBM round-trip, one fewer
// dispatch. LDS 34.6KB -> 4 blocks/CU (need 2.5).
#define XR(t) xr[(t) + ((t) >> 5)]
#define YF(t) yf[(t) + ((t) >> 5)]
__global__ __launch_bounds__(64) void k_filt_resample(const float* __restrict__ xs,
                                                      float* __restrict__ xn,
                                                      const float* __restrict__ hglob,
                                                      FiltArg c, CorArg co) {
  __shared__ float xr[2112];      // extended input seq; later the filtered row
  __shared__ double yf[2112];     // corrected forward output (padded)
  __shared__ double Fs[64][7];
  __shared__ double Zs[64][7];
  __shared__ float hl[526];
  int r = blockIdx.x;
  int k = threadIdx.x;
  const float* x = xs + (size_t)r * 2000;

  for (int i = k; i < 526; i += 64) hl[i] = hglob[i];
  float x0f = x[0], xlf = x[1999];
  for (int t = k; t < 2048; t += 64) {
    float v;
    if (t < 21)        v = 2.f * x0f - x[21 - t];
    else if (t < 2021) v = x[t - 21];
    else if (t < 2042) v = 2.f * xlf - x[4019 - t];
    else               v = 0.f;
    XR(t) = v;
  }
  __syncthreads();

  double b0[3], b1[3], b2[3], a1[3], a2[3];
  #pragma unroll
  for (int s = 0; s < 3; s++) {
    b0[s] = c.b0[s]; b1[s] = c.b1[s]; b2[s] = c.b2[s];
    a1[s] = c.a1[s]; a2[s] = c.a2[s];
  }
  auto step = [&](double* z, double v) -> double {
    #pragma unroll
    for (int s = 0; s < 3; s++) {
      double y = b0[s] * v + z[2 * s];
      z[2 * s]     = b1[s] * v - a1[s] * y + z[2 * s + 1];
      z[2 * s + 1] = b2[s] * v - a2[s] * y;
      v = y;
    }
    return v;
  };
  double arow[6] = {0, 0, 0, 0, 0, 0};
  if (k < 6) {
    #pragma unroll
    for (int j = 0; j < 6; j++) arow[j] = c.A32[k * 6 + j];
  }
  int li = (k < 6) ? k : 0;
  auto scan = [&](double seed) {
    double zz = 0.0;
    if (k < 6) zz = ((k & 1) ? c.zi1[k >> 1] : c.zi0[k >> 1]) * seed;
    for (int kk = 0; kk < 64; kk++) {
      if (k < 6) Zs[kk][k] = zz;
      double f = Fs[kk][li];
      double nz = f;
      #pragma unroll
      for (int j = 0; j < 6; j++) nz += arow[j] * __shfl(zz, j, 64);
      zz = nz;
    }
  };

  int t0 = k * 32;
  double z[6], yreg[32];

  // ---- forward: zero-state pass (registers) ----
  #pragma unroll
  for (int i = 0; i < 6; i++) z[i] = 0.0;
  for (int i = 0; i < 32; i++) yreg[i] = step(z, (double)XR(t0 + i));
  #pragma unroll
  for (int i = 0; i < 6; i++) Fs[k][i] = z[i];
  __syncthreads();
  scan((double)XR(0));
  __syncthreads();
  #pragma unroll
  for (int i = 0; i < 6; i++) z[i] = Zs[k][i];
  for (int i = 0; i < 32; i++) {
    double corr = 0.0;
    #pragma unroll
    for (int j = 0; j < 6; j++) corr += co.CA[i * 6 + j] * z[j];
    YF(t0 + i) = yreg[i] + corr;
  }
  __syncthreads();

  // ---- backward over reversed yf ----
  auto rin = [&](int j) -> double { return (j <= 2041) ? YF(2041 - j) : 0.0; };
  #pragma unroll
  for (int i = 0; i < 6; i++) z[i] = 0.0;
  for (int i = 0; i < 32; i++) yreg[i] = step(z, rin(t0 + i));
  #pragma unroll
  for (int i = 0; i < 6; i++) Fs[k][i] = z[i];
  __syncthreads();
  scan(YF(2041));
  __syncthreads();
  #pragma unroll
  for (int i = 0; i < 6; i++) z[i] = Zs[k][i];
  for (int i = 0; i < 32; i++) {
    int j = t0 + i;
    if (j >= 21 && j <= 2020) {
      double corr = 0.0;
      #pragma unroll
      for (int jj = 0; jj < 6; jj++) corr += co.CA[i * 6 + jj] * z[jj];
      XR(2020 - j) = (float)(yreg[i] + corr);  // filtered row into LDS (reversed+trimmed)
    }
  }
  __syncthreads();

  // ---- polyphase resample (16 up / 25 down) + tanh, from LDS row ----
  float vals[20];
  #pragma unroll 4
  for (int j = 0; j < 20; j++) {
    int o = k + j * 64;                        // 1280 outputs per row
    int P = 25 * (o + 11);
    int phase = P & 15;
    float acc = 0.f;
    for (int m = phase; m <= 525; m += 16) {
      int idx = (P - m) >> 4;
      if (idx >= 0 && idx < 2000) acc += hl[m] * XR(idx);
    }
    vals[j] = tanhf(acc);
  }
  double s = 0.0, ss = 0.0;
  #pragma unroll
  for (int j = 0; j < 20; j++) {
    s += (double)vals[j]; ss += (double)vals[j] * (double)vals[j];
  }
  s = waveReduceSum(s); ss = waveReduceSum(ss);
  s = __shfl(s, 0, 64); ss = __shfl(ss, 0, 64);
  double mean = s / 1280.0;
  double var = (ss - 1280.0 * mean * mean) / 1279.0;
  double sd = fmax(sqrt(fmax(var, 0.0)), 1e-6);
  float fmean = (float)mean, finv = (float)(1.0 / sd);
  float* xo = xn + (size_t)r * 1280;
  #pragma unroll
  for (int j = 0; j < 20; j++)
    xo[k + j * 64] = (vals[j] - fmean) * finv;
}

// ---------------- kernel 3: conv1d + relu + LN + PE(table) + QKV (fused) ------
__global__ __launch_bounds__(256) void k_conv_ln_pe_qkv(const float* __restrict__ xn,
    const float* __restrict__ cw, const float* __restrict__ cb,
    const float* __restrict__ g0, const float* __restrict__ bt0,
    const float* __restrict__ wqkv, const float* __restrict__ bqkv,
    const float* __restrict__ pe,
    float* __restrict__ x0,
    float* __restrict__ Q, float* __restrict__ K, float* __restrict__ V) {
  __shared__ float w[480], bias[16], gg[16], gb[16];
  __shared__ float wq[768], bq[48];
  for (int i = threadIdx.x; i < 480; i += 256) w[i] = cw[i];
  for (int i = threadIdx.x; i < 768; i += 256) wq[i] = wqkv[i];
  if (threadIdx.x < 16) {
    bias[threadIdx.x] = cb[threadIdx.x];
    gg[threadIdx.x] = g0[threadIdx.x];
    gb[threadIdx.x] = bt0[threadIdx.x];
  }
  if (threadIdx.x < 48) bq[threadIdx.x] = bqkv[threadIdx.x];
  __syncthreads();
  int idx = blockIdx.x * 256 + threadIdx.x;
  int b = idx / 1280, t = idx % 1280;
  const float* xb = xn + (size_t)b * 10 * 1280;
  float in[10][3];
  #pragma unroll
  for (int i = 0; i < 10; i++)
    #pragma unroll
    for (int k = 0; k < 3; k++) {
      int tt = t - 1 + k;
      in[i][k] = (tt >= 0 && tt < 1280) ? xb[i * 1280 + tt] : 0.f;
    }
  float o[16];
  #pragma unroll
  for (int oc = 0; oc < 16; oc++) {
    float a = bias[oc];
    #pragma unroll
    for (int i = 0; i < 10; i++)
      #pragma unroll
      for (int k = 0; k < 3; k++) a += in[i][k] * w[oc * 30 + i * 3 + k];
    o[oc] = fmaxf(a, 0.f);
  }
  float mu = 0.f;
  #pragma unroll
  for (int d = 0; d < 16; d++) mu += o[d];
  mu *= (1.f / 16.f);
  float var = 0.f;
  #pragma unroll
  for (int d = 0; d < 16; d++) { float dd = o[d] - mu; var += dd * dd; }
  var *= (1.f / 16.f);
  float inv = 1.f / sqrtf(var + 1e-5f);
  float xv[16];
  float* outp = x0 + (size_t)idx * 16;
  const float* pep = pe + t * 16;
  #pragma unroll
  for (int d = 0; d < 16; d++) {
    xv[d] = (o[d] - mu) * inv * gg[d] + gb[d] + pep[d];
    outp[d] = xv[d];
  }
  float* qp = Q + (size_t)idx * 16;
  float* kp = K + (size_t)idx * 16;
  float* vp = V + (size_t)idx * 16;
  #pragma unroll
  for (int j = 0; j < 16; j++) {
    float a = bq[j];
    #pragma unroll
    for (int d = 0; d < 16; d++) a += xv[d] * wq[j * 16 + d];
    qp[j] = a;
  }
  #pragma unroll
  for (int j = 0; j < 16; j++) {
    float a = bq[16 + j];
    #pragma unroll
    for (int d = 0; d < 16; d++) a += xv[d] * wq[(16 + j) * 16 + d];
    kp[j] = a;
  }
  #pragma unroll
  for (int j = 0; j < 16; j++) {
    float a = bq[32 + j];
    #pragma unroll
    for (int d = 0; d < 16; d++) a += xv[d] * wq[(32 + j) * 16 + d];
    vp[j] = a;
  }
}

// ---------------- kernel 4: MFMA attention ------------------------------------
#define ATT_SHIFT 12.0f
__global__ __launch_bounds__(256) void k_attn_mfma(const float* __restrict__ Q,
    const float* __restrict__ K, const float* __restrict__ V,
    float* __restrict__ A) {
  __shared__ __align__(16) _Float16 Ks[64 * 40];   // [key][d], d 16..31 zero
  __shared__ __align__(16) _Float16 Vt[16 * 72];   // [d][key]
  __shared__ __align__(16) _Float16 Pld[4][16 * 40]; // per-wave [qrow][key32]
  int tid = threadIdx.x;
  int b  = blockIdx.x / 20;
  int rg = blockIdx.x % 20;
  int wv = tid >> 6;
  int lane = tid & 63;
  int col = lane & 15;
  int quad = lane >> 4;
  size_t base = (size_t)b * 1280;
  int row0 = rg * 64 + wv * 16;

  f16x8 qf;
  #pragma unroll
  for (int j = 0; j < 8; j++) qf[j] = (_Float16)0.f;
  if (quad < 2) {
    const float* qp = Q + (base + row0 + col) * 16 + quad * 8;
    #pragma unroll
    for (int j = 0; j < 8; j++) qf[j] = (_Float16)(0.25f * qp[j]);
  }
  f32x4 oacc = {0.f, 0.f, 0.f, 0.f};
  float lacc = 0.f;

  for (int s = 0; s < 20; s++) {
    __syncthreads();
    {
      int key = tid >> 2, part = tid & 3;
      const float* kp = K + (base + s * 64 + key) * 16 + part * 4;
      f16x4 hk, hz;
      #pragma unroll
      for (int j = 0; j < 4; j++) { hk[j] = (_Float16)kp[j]; hz[j] = (_Float16)0.f; }
      *(f16x4*)&Ks[key * 40 + part * 4] = hk;
      *(f16x4*)&Ks[key * 40 + 16 + part * 4] = hz;
      const float* vp = V + (base + s * 64 + key) * 16 + part * 4;
      #pragma unroll
      for (int j = 0; j < 4; j++) Vt[(part * 4 + j) * 72 + key] = (_Float16)vp[j];
    }
    __syncthreads();
    #pragma unroll
    for (int c = 0; c < 2; c++) {
      #pragma unroll
      for (int t = 0; t < 2; t++) {
        int keyoff = c * 32 + t * 16;
        f16x8 af = *(f16x8*)&Ks[(keyoff + col) * 40 + quad * 8];
        f32x4 sf = {0.f, 0.f, 0.f, 0.f};
        sf = __builtin_amdgcn_mfma_f32_16x16x32_f16(af, qf, sf, 0, 0, 0);
        f16x4 ph;
        float psum = 0.f;
        #pragma unroll
        for (int r = 0; r < 4; r++) {
          float p = __expf(sf[r] - ATT_SHIFT);
          psum += p;
          ph[r] = (_Float16)p;
        }
        lacc += psum;
        *(f16x4*)&Pld[wv][col * 40 + t * 16 + quad * 4] = ph;
      }
      __syncthreads();
      f16x8 pf = *(f16x8*)&Pld[wv][col * 40 + quad * 8];
      f16x8 vf = *(f16x8*)&Vt[col * 72 + c * 32 + quad * 8];
      oacc = __builtin_amdgcn_mfma_f32_16x16x32_f16(pf, vf, oacc, 0, 0, 0);
      __syncthreads();
    }
  }
  lacc += __shfl_xor(lacc, 16, 64);
  lacc += __shfl_xor(lacc, 32, 64);
  #pragma unroll
  for (int r = 0; r < 4; r++) {
    float lr = __shfl(lacc, quad * 4 + r, 64);
    A[(base + row0 + quad * 4 + r) * 16 + col] = oacc[r] / lr;
  }
}

// ---------------- kernel 5: combine + wo + LN1 + FFN + LN2 + pool (fused) -----
__global__ __launch_bounds__(256) void k_combine_pool(
    const float* __restrict__ A, const float* __restrict__ x0,
    const float* __restrict__ wo, const float* __restrict__ bo,
    const float* __restrict__ w1, const float* __restrict__ b1,
    const float* __restrict__ w2, const float* __restrict__ b2,
    const float* __restrict__ g1, const float* __restrict__ bb1,
    const float* __restrict__ g2, const float* __restrict__ bb2,
    const float* __restrict__ wfc, const float* __restrict__ bfc,
    float* __restrict__ out) {
  __shared__ float swo[256], sw1[512], sw2[512];
  __shared__ float sbo[16], sb1[32], sb2[16], sg1[16], sbb1[16], sg2[16], sbb2[16];
  __shared__ float swf[16];
  int tid = threadIdx.x;
  swo[tid] = wo[tid];
  for (int i = tid; i < 512; i += 256) { sw1[i] = w1[i]; sw2[i] = w2[i]; }
  if (tid < 16) {
    sbo[tid] = bo[tid]; sb2[tid] = b2[tid];
    sg1[tid] = g1[tid]; sbb1[tid] = bb1[tid];
    sg2[tid] = g2[tid]; sbb2[tid] = bb2[tid];
    swf[tid] = wfc[tid];
  }
  if (tid < 32) sb1[tid] = b1[tid];
  __syncthreads();

  int idx = blockIdx.x * 256 + tid;          // [0, 81920)
  int bb = blockIdx.x / 5;
  const float* pa = A + (size_t)idx * 16;
  float a[16];
  #pragma unroll
  for (int d = 0; d < 16; d++) a[d] = pa[d];
  float h[16];
  const float* xr = x0 + (size_t)idx * 16;
  #pragma unroll
  for (int d = 0; d < 16; d++) {
    float o = sbo[d];
    #pragma unroll
    for (int e = 0; e < 16; e++) o += a[e] * swo[d * 16 + e];
    h[d] = xr[d] + o;
  }
  float mu = 0.f;
  #pragma unroll
  for (int d = 0; d < 16; d++) mu += h[d];
  mu *= (1.f / 16.f);
  float var = 0.f;
  #pragma unroll
  for (int d = 0; d < 16; d++) { float dd = h[d] - mu; var += dd * dd; }
  var *= (1.f / 16.f);
  float inv = 1.f / sqrtf(var + 1e-5f);
  float x1[16];
  #pragma unroll
  for (int d = 0; d < 16; d++) x1[d] = (h[d] - mu) * inv * sg1[d] + sbb1[d];
  float t1[32];
  #pragma unroll
  for (int j = 0; j < 32; j++) {
    float u = sb1[j];
    #pragma unroll
    for (int d = 0; d < 16; d++) u += x1[d] * sw1[j * 16 + d];
    t1[j] = fmaxf(u, 0.f);
  }
  float h2[16];
  #pragma unroll
  for (int d = 0; d < 16; d++) {
    float u = sb2[d];
    #pragma unroll
    for (int j = 0; j < 32; j++) u += t1[j] * sw2[d * 32 + j];
    h2[d] = x1[d] + u;
  }
  mu = 0.f;
  #pragma unroll
  for (int d = 0; d < 16; d++) mu += h2[d];
  mu *= (1.f / 16.f);
  var = 0.f;
  #pragma unroll
  for (int d = 0; d < 16; d++) { float dd = h2[d] - mu; var += dd * dd; }
  var *= (1.f / 16.f);
  inv = 1.f / sqrtf(var + 1e-5f);
  float pv = 0.f;
  #pragma unroll
  for (int d = 0; d < 16; d++)
    pv += ((h2[d] - mu) * inv * sg2[d] + sbb2[d]) * swf[d];
  double part = waveReduceSum((double)pv);
  __shared__ double red[4];
  int wid = tid >> 6, lane = tid & 63;
  if (lane == 0) red[wid] = part;
  __syncthreads();
  if (tid == 0) {
    double S = red[0] + red[1] + red[2] + red[3];
    float add = (float)(S / 1280.0);
    if (blockIdx.x % 5 == 0) add += bfc[0];
    atomicAdd(&out[bb], add);
  }
}

// ---------------- launch ------------------------------------------------------
extern "C" void kernel_launch(void* const* d_in, const int* in_sizes, int n_in,
                              void* d_out, int out_size, void* d_ws, size_t ws_size,
                              hipStream_t stream) {
  const float* x    = (const float*)d_in[0];
  const float* cw   = (const float*)d_in[1];
  const float* cb   = (const float*)d_in[2];
  const float* g0   = (const float*)d_in[3];
  const float* bt0  = (const float*)d_in[4];
  const float* wqkv = (const float*)d_in[5];
  const float* bqkv = (const float*)d_in[6];
  const float* wo   = (const float*)d_in[7];
  const float* bo   = (const float*)d_in[8];
  const float* w1   = (const float*)d_in[9];
  const float* b1   = (const float*)d_in[10];
  const float* w2   = (const float*)d_in[11];
  const float* b2   = (const float*)d_in[12];
  const float* g1   = (const float*)d_in[13];
  const float* bb1  = (const float*)d_in[14];
  const float* g2   = (const float*)d_in[15];
  const float* bb2  = (const float*)d_in[16];
  const float* wfc  = (const float*)d_in[17];
  const float* bfc  = (const float*)d_in[18];
  float* out = (float*)d_out;

  float* ws = (float*)d_ws;
  float* xs = ws;                       // 640*2000 = 1,280,000 (demeaned rows;
                                        // dead after k_filt_resample -> reused as A)
  float* y1 = xs + 1280000;             // spacer (dead)
  float* xn = y1 + 1306880;             // 640*1280   =   819,200
  float* x0 = xn + 819200;              // 64*1280*16 = 1,310,720
  float* Q  = x0 + 1310720;
  float* Kb = Q  + 1310720;
  float* Vb = Kb + 1310720;
  float* pe = Vb + 1310720;             // 1280*16 = 20,480
  float* hbuf = pe + 20480;             // 526 FIR taps   (total ~36 MB)
  float* Abuf = ws;                     // attention output (reuses dead xs)

  FiltArg fc; CorArg co;
  build_filt(fc, co);

  k_chansel_pe<<<581, 256, 0, stream>>>(x, xs, pe, hbuf, out);
  k_filt_resample<<<640, 64, 0, stream>>>(xs, xn, hbuf, fc, co);
  k_conv_ln_pe_qkv<<<320, 256, 0, stream>>>(xn, cw, cb, g0, bt0, wqkv, bqkv,
                                            pe, x0, Q, Kb, Vb);
  k_attn_mfma<<<1280, 256, 0, stream>>>(Q, Kb, Vb, Abuf);
  k_combine_pool<<<320, 256, 0, stream>>>(Abuf, x0, wo, bo, w1, b1, w2, b2,
                                          g1, bb1, g2, bb2, wfc, bfc, out);
}

// Round 13
// 256.343 us; speedup vs baseline: 1.1579x; 1.1579x over previous
//
#include <hip/hip_runtime.h>
#include <cmath>
#include <complex>
#include <algorithm>

#ifndef M_PI
#define M_PI 3.14159265358979323846
#endif

typedef _Float16 f16x8 __attribute__((ext_vector_type(8)));
typedef _Float16 f16x4 __attribute__((ext_vector_type(4)));
typedef float f32x4 __attribute__((ext_vector_type(4)));

// ---------------- coefficient structs (passed by value as kernel args) ---------
struct FiltArg {
  double b0[3], b1[3], b2[3], a1[3], a2[3];
  double zi0[3], zi1[3];
  double A32[36];              // (state-transition matrix)^32, 6x6 row-major
};
struct CorArg { double CA[32 * 6]; };  // CA[i][j] = output at step i from unit state e_j
struct FirArg { float h[526]; };  // 25 leading zeros + 501-tap kaiser-sinc, *UP

// ---------------- host-side filter design (exact replica of reference) --------
static void design_sos(FiltArg& sa) {
  const int order = 6;
  const double wn = 0.5 / 50.0;
  const double fs = 2.0;
  double warped = 2.0 * fs * std::tan(M_PI * wn / fs);
  std::complex<double> p[6];
  for (int i = 0; i < order; i++) {
    int m = -order + 1 + 2 * i;                      // -5,-3,-1,1,3,5
    p[i] = -std::exp(std::complex<double>(0.0, M_PI * m / (2.0 * order)));
  }
  std::complex<double> prod1(1, 0);
  for (int i = 0; i < 6; i++) prod1 *= -p[i];
  double k = (1.0 / prod1).real();
  for (int i = 0; i < 6; i++) p[i] = warped / p[i];
  const double fs2 = 2.0 * fs;
  std::complex<double> num(1, 0), den(1, 0);
  for (int i = 0; i < 6; i++) { num *= fs2; den *= (fs2 - p[i]); }
  k *= (num / den).real();
  for (int i = 0; i < 6; i++) p[i] = (fs2 + p[i]) / (fs2 - p[i]);
  std::complex<double> pp[3]; int n = 0;
  for (int i = 0; i < 6; i++) if (p[i].imag() > 0) pp[n++] = p[i];
  std::stable_sort(pp, pp + 3,
    [](const std::complex<double>& A, const std::complex<double>& B) {
      return std::fabs(std::abs(A) - 1.0) > std::fabs(std::abs(B) - 1.0);
    });
  double sos[3][6];
  for (int s = 0; s < 3; s++) {
    double g = (s == 0) ? k : 1.0;
    sos[s][0] = g; sos[s][1] = -2.0 * g; sos[s][2] = g;
    sos[s][3] = 1.0; sos[s][4] = -2.0 * pp[s].real(); sos[s][5] = std::norm(pp[s]);
  }
  double scale = 1.0;
  for (int s = 0; s < 3; s++) {
    double b0 = sos[s][0], b1 = sos[s][1], b2 = sos[s][2];
    double a1 = sos[s][4], a2 = sos[s][5];
    double det = 1.0 + a1 + a2;                      // det of [[1+a1,-1],[a2,1]]
    double r0 = b1 - a1 * b0, r1 = b2 - a2 * b0;
    double z0 = (r0 + r1) / det;
    double z1 = ((1.0 + a1) * r1 - a2 * r0) / det;
    sa.b0[s] = b0; sa.b1[s] = b1; sa.b2[s] = b2; sa.a1[s] = a1; sa.a2[s] = a2;
    sa.zi0[s] = scale * z0; sa.zi1[s] = scale * z1;
    scale *= (b0 + b1 + b2) / (1.0 + a1 + a2);
  }
}

static double host_step(const FiltArg& c, double z[6], double v) {
  for (int s = 0; s < 3; s++) {
    double y = c.b0[s] * v + z[2 * s];
    z[2 * s]     = c.b1[s] * v - c.a1[s] * y + z[2 * s + 1];
    z[2 * s + 1] = c.b2[s] * v - c.a2[s] * y;
    v = y;
  }
  return v;
}

static void build_filt(FiltArg& c, CorArg& co) {
  design_sos(c);
  double A[36];
  for (int j = 0; j < 6; j++) {
    double z[6] = {0, 0, 0, 0, 0, 0};
    z[j] = 1.0;
    host_step(c, z, 0.0);
    for (int i = 0; i < 6; i++) A[i * 6 + j] = z[i];
  }
  double M[36], T[36];
  for (int i = 0; i < 36; i++) M[i] = A[i];
  for (int sq = 0; sq < 5; sq++) {
    for (int i = 0; i < 6; i++)
      for (int j = 0; j < 6; j++) {
        double s = 0.0;
        for (int kk = 0; kk < 6; kk++) s += M[i * 6 + kk] * M[kk * 6 + j];
        T[i * 6 + j] = s;
      }
    for (int i = 0; i < 36; i++) M[i] = T[i];
  }
  for (int i = 0; i < 36; i++) c.A32[i] = M[i];
  // CA[i][j]: output at chunk-step i starting from unit state e_j, zero input
  for (int j = 0; j < 6; j++) {
    double z[6] = {0, 0, 0, 0, 0, 0};
    z[j] = 1.0;
    for (int i = 0; i < 32; i++) co.CA[i * 6 + j] = host_step(c, z, 0.0);
  }
}

static double bessel_i0(double x) {
  double s = 1.0, t = 1.0;
  for (int k = 1; k < 64; k++) {
    double u = x / (2.0 * k);
    t *= u * u; s += t;
    if (t < 1e-18 * s) break;
  }
  return s;
}

static void design_fir(FirArg& fa) {
  double h[501];
  const double fc = 1.0 / 25.0;
  double denom = bessel_i0(5.0);
  double sum = 0.0;
  for (int nn = 0; nn < 501; nn++) {
    double m = nn - 250.0;
    double xx = fc * m;
    double snc = (nn == 250) ? 1.0 : std::sin(M_PI * xx) / (M_PI * xx);
    double r = (2.0 * nn) / 500.0 - 1.0;
    double w = bessel_i0(5.0 * std::sqrt(std::max(0.0, 1.0 - r * r))) / denom;
    h[nn] = fc * snc * w; sum += h[nn];
  }
  for (int nn = 0; nn < 25; nn++) fa.h[nn] = 0.0f;          // n_pre_pad = 25
  for (int nn = 0; nn < 501; nn++) fa.h[25 + nn] = (float)(h[nn] / sum * 16.0);
}

// ---------------- device helpers ----------------
__device__ inline double waveReduceSum(double v) {
  #pragma unroll
  for (int off = 32; off > 0; off >>= 1) v += __shfl_down(v, off, 64);
  return v;
}

// ---------------- kernel 1: chansel + demean, PE table, out-zero (merged) -----
__global__ __launch_bounds__(256) void k_chansel_pe(const float* __restrict__ x,
                                                    float* __restrict__ xs,
                                                    float* __restrict__ pe,
                                                    float* __restrict__ out) {
  int gid = blockIdx.x;
  if (gid < 500) {
    int idx = gid * 256 + threadIdx.x;
    int b = idx / 2000, t = idx % 2000;
    const int ch[10] = {126, 125, 48, 112, 67, 93, 10, 61, 39, 108};
    const float* xb = x + (size_t)b * 128 * 2000;
    float v[10]; float s = 0.f;
    #pragma unroll
    for (int c = 0; c < 10; c++) { v[c] = xb[ch[c] * 2000 + t]; s += v[c]; }
    s *= 0.1f;
    #pragma unroll
    for (int c = 0; c < 10; c++) xs[((size_t)b * 10 + c) * 2000 + t] = v[c] - s;
  } else {
    int i = (gid - 500) * 256 + threadIdx.x;    // [0, 20480)
    int t = i >> 4, d = i & 15, j = d >> 1;
    double div = exp(-((double)(2 * j)) * 0.5756462732485114); // ln(10000)/16
    double a = (double)t * div;
    pe[i] = (float)((d & 1) ? cos(a) : sin(a));
    if (gid == 579 && threadIdx.x < 64) out[threadIdx.x] = 0.f;
  }
}

// ---------------- kernel 2: filtfilt, register pass1 + parallel correction ----
// (round-9/11 measured-best version, 43.5us. Round-12's fusion of resample
// into this 64-thread kernel regressed to 104us -- resample must stay in its
// own 256-thread throughput-regime kernel.)
#define XR(t) xr[(t) + ((t) >> 5)]
#define YF(t) yf[(t) + ((t) >> 5)]
__global__ __launch_bounds__(64) void k_filtfilt(float* __restrict__ xs,
                                                 FiltArg c, CorArg co) {
  __shared__ float xr[2112];      // extended input seq (padded)
  __shared__ double yf[2112];     // corrected forward output (padded)
  __shared__ double Fs[64][7];
  __shared__ double Zs[64][7];
  int r = blockIdx.x;
  int k = threadIdx.x;
  float* x = xs + (size_t)r * 2000;

  float x0f = x[0], xlf = x[1999];
  for (int t = k; t < 2048; t += 64) {
    float v;
    if (t < 21)        v = 2.f * x0f - x[21 - t];
    else if (t < 2021) v = x[t - 21];
    else if (t < 2042) v = 2.f * xlf - x[4019 - t];
    else               v = 0.f;
    XR(t) = v;
  }
  __syncthreads();

  double b0[3], b1[3], b2[3], a1[3], a2[3];
  #pragma unroll
  for (int s = 0; s < 3; s++) {
    b0[s] = c.b0[s]; b1[s] = c.b1[s]; b2[s] = c.b2[s];
    a1[s] = c.a1[s]; a2[s] = c.a2[s];
  }
  auto step = [&](double* z, double v) -> double {
    #pragma unroll
    for (int s = 0; s < 3; s++) {
      double y = b0[s] * v + z[2 * s];
      z[2 * s]     = b1[s] * v - a1[s] * y + z[2 * s + 1];
      z[2 * s + 1] = b2[s] * v - a2[s] * y;
      v = y;
    }
    return v;
  };
  double arow[6] = {0, 0, 0, 0, 0, 0};
  if (k < 6) {
    #pragma unroll
    for (int j = 0; j < 6; j++) arow[j] = c.A32[k * 6 + j];
  }
  int li = (k < 6) ? k : 0;
  auto scan = [&](double seed) {
    double zz = 0.0;
    if (k < 6) zz = ((k & 1) ? c.zi1[k >> 1] : c.zi0[k >> 1]) * seed;
    for (int kk = 0; kk < 64; kk++) {
      if (k < 6) Zs[kk][k] = zz;
      double f = Fs[kk][li];
      double nz = f;
      #pragma unroll
      for (int j = 0; j < 6; j++) nz += arow[j] * __shfl(zz, j, 64);
      zz = nz;
    }
  };

  int t0 = k * 32;
  double z[6], yreg[32];

  #pragma unroll
  for (int i = 0; i < 6; i++) z[i] = 0.0;
  for (int i = 0; i < 32; i++) yreg[i] = step(z, (double)XR(t0 + i));
  #pragma unroll
  for (int i = 0; i < 6; i++) Fs[k][i] = z[i];
  __syncthreads();
  scan((double)XR(0));
  __syncthreads();
  #pragma unroll
  for (int i = 0; i < 6; i++) z[i] = Zs[k][i];
  for (int i = 0; i < 32; i++) {
    double corr = 0.0;
    #pragma unroll
    for (int j = 0; j < 6; j++) corr += co.CA[i * 6 + j] * z[j];
    YF(t0 + i) = yreg[i] + corr;
  }
  __syncthreads();

  auto rin = [&](int j) -> double { return (j <= 2041) ? YF(2041 - j) : 0.0; };
  #pragma unroll
  for (int i = 0; i < 6; i++) z[i] = 0.0;
  for (int i = 0; i < 32; i++) yreg[i] = step(z, rin(t0 + i));
  #pragma unroll
  for (int i = 0; i < 6; i++) Fs[k][i] = z[i];
  __syncthreads();
  scan(YF(2041));
  __syncthreads();
  #pragma unroll
  for (int i = 0; i < 6; i++) z[i] = Zs[k][i];
  for (int i = 0; i < 32; i++) {
    int j = t0 + i;
    if (j >= 21 && j <= 2020) {
      double corr = 0.0;
      #pragma unroll
      for (int jj = 0; jj < 6; jj++) corr += co.CA[i * 6 + jj] * z[jj];
      x[2020 - j] = (float)(yreg[i] + corr);   // reversed + trimmed
    }
  }
}

// ---------------- kernel 3: polyphase resample + tanh + per-row normalize ----
__global__ __launch_bounds__(256) void k_resample_norm(const float* __restrict__ xf,
                                                       float* __restrict__ xn,
                                                       FirArg fa) {
  __shared__ float xl[2000];
  __shared__ float hl[526];
  int r = blockIdx.x;                         // 640 rows
  const float* x = xf + (size_t)r * 2000;
  for (int i = threadIdx.x; i < 2000; i += 256) xl[i] = x[i];
  for (int i = threadIdx.x; i < 526; i += 256) hl[i] = fa.h[i];
  __syncthreads();
  float vals[5];
  #pragma unroll
  for (int kk = 0; kk < 5; kk++) {
    int o = threadIdx.x + kk * 256;           // 1280 outputs per row
    int P = 25 * (o + 11);
    int phase = P & 15;
    float acc = 0.f;
    for (int m = phase; m <= 525; m += 16) {
      int idx = (P - m) >> 4;
      if (idx >= 0 && idx < 2000) acc += hl[m] * xl[idx];
    }
    vals[kk] = tanhf(acc);
  }
  double s = 0.0, ss = 0.0;
  #pragma unroll
  for (int kk = 0; kk < 5; kk++) {
    s += (double)vals[kk]; ss += (double)vals[kk] * (double)vals[kk];
  }
  s = waveReduceSum(s); ss = waveReduceSum(ss);
  __shared__ double red[8];
  int wid = threadIdx.x >> 6, lane = threadIdx.x & 63;
  if (lane == 0) { red[wid] = s; red[4 + wid] = ss; }
  __syncthreads();
  double S = red[0] + red[1] + red[2] + red[3];
  double SS = red[4] + red[5] + red[6] + red[7];
  double mean = S / 1280.0;
  double var = (SS - 1280.0 * mean * mean) / 1279.0;
  double sd = fmax(sqrt(fmax(var, 0.0)), 1e-6);
  float fmean = (float)mean, finv = (float)(1.0 / sd);
  #pragma unroll
  for (int kk = 0; kk < 5; kk++)
    xn[(size_t)r * 1280 + threadIdx.x + kk * 256] = (vals[kk] - fmean) * finv;
}

// ---------------- kernel 4: conv1d + relu + LN + PE(table) + QKV (fused) ------
__global__ __launch_bounds__(256) void k_conv_ln_pe_qkv(const float* __restrict__ xn,
    const float* __restrict__ cw, const float* __restrict__ cb,
    const float* __restrict__ g0, const float* __restrict__ bt0,
    const float* __restrict__ wqkv, const float* __restrict__ bqkv,
    const float* __restrict__ pe,
    float* __restrict__ x0,
    float* __restrict__ Q, float* __restrict__ K, float* __restrict__ V) {
  __shared__ float w[480], bias[16], gg[16], gb[16];
  __shared__ float wq[768], bq[48];
  for (int i = threadIdx.x; i < 480; i += 256) w[i] = cw[i];
  for (int i = threadIdx.x; i < 768; i += 256) wq[i] = wqkv[i];
  if (threadIdx.x < 16) {
    bias[threadIdx.x] = cb[threadIdx.x];
    gg[threadIdx.x] = g0[threadIdx.x];
    gb[threadIdx.x] = bt0[threadIdx.x];
  }
  if (threadIdx.x < 48) bq[threadIdx.x] = bqkv[threadIdx.x];
  __syncthreads();
  int idx = blockIdx.x * 256 + threadIdx.x;
  int b = idx / 1280, t = idx % 1280;
  const float* xb = xn + (size_t)b * 10 * 1280;
  float in[10][3];
  #pragma unroll
  for (int i = 0; i < 10; i++)
    #pragma unroll
    for (int k = 0; k < 3; k++) {
      int tt = t - 1 + k;
      in[i][k] = (tt >= 0 && tt < 1280) ? xb[i * 1280 + tt] : 0.f;
    }
  float o[16];
  #pragma unroll
  for (int oc = 0; oc < 16; oc++) {
    float a = bias[oc];
    #pragma unroll
    for (int i = 0; i < 10; i++)
      #pragma unroll
      for (int k = 0; k < 3; k++) a += in[i][k] * w[oc * 30 + i * 3 + k];
    o[oc] = fmaxf(a, 0.f);
  }
  float mu = 0.f;
  #pragma unroll
  for (int d = 0; d < 16; d++) mu += o[d];
  mu *= (1.f / 16.f);
  float var = 0.f;
  #pragma unroll
  for (int d = 0; d < 16; d++) { float dd = o[d] - mu; var += dd * dd; }
  var *= (1.f / 16.f);
  float inv = 1.f / sqrtf(var + 1e-5f);
  float xv[16];
  float* outp = x0 + (size_t)idx * 16;
  const float* pep = pe + t * 16;
  #pragma unroll
  for (int d = 0; d < 16; d++) {
    xv[d] = (o[d] - mu) * inv * gg[d] + gb[d] + pep[d];
    outp[d] = xv[d];
  }
  float* qp = Q + (size_t)idx * 16;
  float* kp = K + (size_t)idx * 16;
  float* vp = V + (size_t)idx * 16;
  #pragma unroll
  for (int j = 0; j < 16; j++) {
    float a = bq[j];
    #pragma unroll
    for (int d = 0; d < 16; d++) a += xv[d] * wq[j * 16 + d];
    qp[j] = a;
  }
  #pragma unroll
  for (int j = 0; j < 16; j++) {
    float a = bq[16 + j];
    #pragma unroll
    for (int d = 0; d < 16; d++) a += xv[d] * wq[(16 + j) * 16 + d];
    kp[j] = a;
  }
  #pragma unroll
  for (int j = 0; j < 16; j++) {
    float a = bq[32 + j];
    #pragma unroll
    for (int d = 0; d < 16; d++) a += xv[d] * wq[(32 + j) * 16 + d];
    vp[j] = a;
  }
}

// ---------------- kernel 5: MFMA attention ------------------------------------
// Barrier diet: only the 2 staging barriers per s-tile (cross-wave Ks/Vt
// hazards) remain. The 4 per-c barriers around Pld are gone -- Pld[wv] is
// per-wave LDS: same-wave DS ops execute in issue order and the compiler
// preserves program order for potentially-aliasing LDS accesses (lgkmcnt
// waits auto-inserted), so no block-wide rendezvous is needed.
#define ATT_SHIFT 12.0f
__global__ __launch_bounds__(256) void k_attn_mfma(const float* __restrict__ Q,
    const float* __restrict__ K, const float* __restrict__ V,
    float* __restrict__ A) {
  __shared__ __align__(16) _Float16 Ks[64 * 40];   // [key][d], d 16..31 zero
  __shared__ __align__(16) _Float16 Vt[16 * 72];   // [d][key]
  __shared__ __align__(16) _Float16 Pld[4][16 * 40]; // per-wave [qrow][key32]
  int tid = threadIdx.x;
  int b  = blockIdx.x / 20;
  int rg = blockIdx.x % 20;
  int wv = tid >> 6;
  int lane = tid & 63;
  int col = lane & 15;
  int quad = lane >> 4;
  size_t base = (size_t)b * 1280;
  int row0 = rg * 64 + wv * 16;

  f16x8 qf;
  #pragma unroll
  for (int j = 0; j < 8; j++) qf[j] = (_Float16)0.f;
  if (quad < 2) {
    const float* qp = Q + (base + row0 + col) * 16 + quad * 8;
    #pragma unroll
    for (int j = 0; j < 8; j++) qf[j] = (_Float16)(0.25f * qp[j]);
  }
  f32x4 oacc = {0.f, 0.f, 0.f, 0.f};
  float lacc = 0.f;

  for (int s = 0; s < 20; s++) {
    __syncthreads();                       // Ks/Vt safe to overwrite
    {
      int key = tid >> 2, part = tid & 3;
      const float* kp = K + (base + s * 64 + key) * 16 + part * 4;
      f16x4 hk, hz;
      #pragma unroll
      for (int j = 0; j < 4; j++) { hk[j] = (_Float16)kp[j]; hz[j] = (_Float16)0.f; }
      *(f16x4*)&Ks[key * 40 + part * 4] = hk;
      *(f16x4*)&Ks[key * 40 + 16 + part * 4] = hz;
      const float* vp = V + (base + s * 64 + key) * 16 + part * 4;
      #pragma unroll
      for (int j = 0; j < 4; j++) Vt[(part * 4 + j) * 72 + key] = (_Float16)vp[j];
    }
    __syncthreads();                       // Ks/Vt visible to all waves
    #pragma unroll
    for (int c = 0; c < 2; c++) {
      #pragma unroll
      for (int t = 0; t < 2; t++) {
        int keyoff = c * 32 + t * 16;
        f16x8 af = *(f16x8*)&Ks[(keyoff + col) * 40 + quad * 8];
        f32x4 sf = {0.f, 0.f, 0.f, 0.f};
        sf = __builtin_amdgcn_mfma_f32_16x16x32_f16(af, qf, sf, 0, 0, 0);
        f16x4 ph;
        float psum = 0.f;
        #pragma unroll
        for (int r = 0; r < 4; r++) {
          float p = __expf(sf[r] - ATT_SHIFT);
          psum += p;
          ph[r] = (_Float16)p;
        }
        lacc += psum;
        *(f16x4*)&Pld[wv][col * 40 + t * 16 + quad * 4] = ph;
      }
      // no barrier: Pld[wv] is per-wave, same-wave DS ops are in-order
      f16x8 pf = *(f16x8*)&Pld[wv][col * 40 + quad * 8];
      f16x8 vf = *(f16x8*)&Vt[col * 72 + c * 32 + quad * 8];
      oacc = __builtin_amdgcn_mfma_f32_16x16x32_f16(pf, vf, oacc, 0, 0, 0);
    }
  }
  lacc += __shfl_xor(lacc, 16, 64);
  lacc += __shfl_xor(lacc, 32, 64);
  #pragma unroll
  for (int r = 0; r < 4; r++) {
    float lr = __shfl(lacc, quad * 4 + r, 64);
    A[(base + row0 + quad * 4 + r) * 16 + col] = oacc[r] / lr;
  }
}

// ---------------- kernel 6: combine + wo + LN1 + FFN + LN2 + pool (fused) -----
__global__ __launch_bounds__(256) void k_combine_pool(
    const float* __restrict__ A, const float* __restrict__ x0,
    const float* __restrict__ wo, const float* __restrict__ bo,
    const float* __restrict__ w1, const float* __restrict__ b1,
    const float* __restrict__ w2, const float* __restrict__ b2,
    const float* __restrict__ g1, const float* __restrict__ bb1,
    const float* __restrict__ g2, const float* __restrict__ bb2,
    const float* __restrict__ wfc, const float* __restrict__ bfc,
    float* __restrict__ out) {
  __shared__ float swo[256], sw1[512], sw2[512];
  __shared__ float sbo[16], sb1[32], sb2[16], sg1[16], sbb1[16], sg2[16], sbb2[16];
  __shared__ float swf[16];
  int tid = threadIdx.x;
  swo[tid] = wo[tid];
  for (int i = tid; i < 512; i += 256) { sw1[i] = w1[i]; sw2[i] = w2[i]; }
  if (tid < 16) {
    sbo[tid] = bo[tid]; sb2[tid] = b2[tid];
    sg1[tid] = g1[tid]; sbb1[tid] = bb1[tid];
    sg2[tid] = g2[tid]; sbb2[tid] = bb2[tid];
    swf[tid] = wfc[tid];
  }
  if (tid < 32) sb1[tid] = b1[tid];
  __syncthreads();

  int idx = blockIdx.x * 256 + tid;          // [0, 81920)
  int bb = blockIdx.x / 5;
  const float* pa = A + (size_t)idx * 16;
  float a[16];
  #pragma unroll
  for (int d = 0; d < 16; d++) a[d] = pa[d];
  float h[16];
  const float* xr = x0 + (size_t)idx * 16;
  #pragma unroll
  for (int d = 0; d < 16; d++) {
    float o = sbo[d];
    #pragma unroll
    for (int e = 0; e < 16; e++) o += a[e] * swo[d * 16 + e];
    h[d] = xr[d] + o;
  }
  float mu = 0.f;
  #pragma unroll
  for (int d = 0; d < 16; d++) mu += h[d];
  mu *= (1.f / 16.f);
  float var = 0.f;
  #pragma unroll
  for (int d = 0; d < 16; d++) { float dd = h[d] - mu; var += dd * dd; }
  var *= (1.f / 16.f);
  float inv = 1.f / sqrtf(var + 1e-5f);
  float x1[16];
  #pragma unroll
  for (int d = 0; d < 16; d++) x1[d] = (h[d] - mu) * inv * sg1[d] + sbb1[d];
  float t1[32];
  #pragma unroll
  for (int j = 0; j < 32; j++) {
    float u = sb1[j];
    #pragma unroll
    for (int d = 0; d < 16; d++) u += x1[d] * sw1[j * 16 + d];
    t1[j] = fmaxf(u, 0.f);
  }
  float h2[16];
  #pragma unroll
  for (int d = 0; d < 16; d++) {
    float u = sb2[d];
    #pragma unroll
    for (int j = 0; j < 32; j++) u += t1[j] * sw2[d * 32 + j];
    h2[d] = x1[d] + u;
  }
  mu = 0.f;
  #pragma unroll
  for (int d = 0; d < 16; d++) mu += h2[d];
  mu *= (1.f / 16.f);
  var = 0.f;
  #pragma unroll
  for (int d = 0; d < 16; d++) { float dd = h2[d] - mu; var += dd * dd; }
  var *= (1.f / 16.f);
  inv = 1.f / sqrtf(var + 1e-5f);
  float pv = 0.f;
  #pragma unroll
  for (int d = 0; d < 16; d++)
    pv += ((h2[d] - mu) * inv * sg2[d] + sbb2[d]) * swf[d];
  double part = waveReduceSum((double)pv);
  __shared__ double red[4];
  int wid = tid >> 6, lane = tid & 63;
  if (lane == 0) red[wid] = part;
  __syncthreads();
  if (tid == 0) {
    double S = red[0] + red[1] + red[2] + red[3];
    float add = (float)(S / 1280.0);
    if (blockIdx.x % 5 == 0) add += bfc[0];
    atomicAdd(&out[bb], add);
  }
}

// ---------------- launch ------------------------------------------------------
extern "C" void kernel_launch(void* const* d_in, const int* in_sizes, int n_in,
                              void* d_out, int out_size, void* d_ws, size_t ws_size,
                              hipStream_t stream) {
  const float* x    = (const float*)d_in[0];
  const float* cw   = (const float*)d_in[1];
  const float* cb   = (const float*)d_in[2];
  const float* g0   = (const float*)d_in[3];
  const float* bt0  = (const float*)d_in[4];
  const float* wqkv = (const float*)d_in[5];
  const float* bqkv = (const float*)d_in[6];
  const float* wo   = (const float*)d_in[7];
  const float* bo   = (const float*)d_in[8];
  const float* w1   = (const float*)d_in[9];
  const float* b1   = (const float*)d_in[10];
  const float* w2   = (const float*)d_in[11];
  const float* b2   = (const float*)d_in[12];
  const float* g1   = (const float*)d_in[13];
  const float* bb1  = (const float*)d_in[14];
  const float* g2   = (const float*)d_in[15];
  const float* bb2  = (const float*)d_in[16];
  const float* wfc  = (const float*)d_in[17];
  const float* bfc  = (const float*)d_in[18];
  float* out = (float*)d_out;

  float* ws = (float*)d_ws;
  float* xs = ws;                       // 640*2000 = 1,280,000 (filtered in-place;
                                        // dead after k_resample_norm -> reused as A)
  float* y1 = xs + 1280000;             // spacer (dead)
  float* xn = y1 + 1306880;             // 640*1280   =   819,200
  float* x0 = xn + 819200;              // 64*1280*16 = 1,310,720
  float* Q  = x0 + 1310720;
  float* Kb = Q  + 1310720;
  float* Vb = Kb + 1310720;
  float* pe = Vb + 1310720;             // 1280*16 = 20,480  (total ~36 MB)
  float* Abuf = ws;                     // attention output (reuses dead xs)

  FiltArg fc; CorArg co; FirArg fa;
  build_filt(fc, co);
  design_fir(fa);

  k_chansel_pe<<<580, 256, 0, stream>>>(x, xs, pe, out);
  k_filtfilt<<<640, 64, 0, stream>>>(xs, fc, co);
  k_resample_norm<<<640, 256, 0, stream>>>(xs, xn, fa);
  k_conv_ln_pe_qkv<<<320, 256, 0, stream>>>(xn, cw, cb, g0, bt0, wqkv, bqkv,
                                            pe, x0, Q, Kb, Vb);
  k_attn_mfma<<<1280, 256, 0, stream>>>(Q, Kb, Vb, Abuf);
  k_combine_pool<<<320, 256, 0, stream>>>(Abuf, x0, wo, bo, w1, b1, w2, b2,
                                          g1, bb1, g2, bb2, wfc, bfc, out);
}

// Round 14
// 252.513 us; speedup vs baseline: 1.1754x; 1.0152x over previous
//
#include <hip/hip_runtime.h>
#include <cmath>
#include <complex>
#include <algorithm>

#ifndef M_PI
#define M_PI 3.14159265358979323846
#endif

typedef _Float16 f16x8 __attribute__((ext_vector_type(8)));
typedef _Float16 f16x4 __attribute__((ext_vector_type(4)));
typedef float f32x4 __attribute__((ext_vector_type(4)));

// ---------------- coefficient structs (passed by value as kernel args) ---------
struct FiltArg {
  double b0[3], b1[3], b2[3], a1[3], a2[3];
  double zi0[3], zi1[3];
};
struct CorArg { double CA[32 * 6]; };  // CA[i][j] = output at step i from unit state e_j
struct EigArg {
  double Pm[36], Pinv[36];   // A32 = Pm · blkdiag(rot(λ_s)) · Pinv
  double czi[6];             // Pinv · (zi vector)
  double lam_re[3], lam_im[3];   // λ_s = p_s^32
  double lami_re[3], lami_im[3]; // λ_s^{-1}
};
struct FirArg { float h[526]; };  // 25 leading zeros + 501-tap kaiser-sinc, *UP

// ---------------- host-side filter design (exact replica of reference) --------
static void design_sos(FiltArg& sa) {
  const int order = 6;
  const double wn = 0.5 / 50.0;
  const double fs = 2.0;
  double warped = 2.0 * fs * std::tan(M_PI * wn / fs);
  std::complex<double> p[6];
  for (int i = 0; i < order; i++) {
    int m = -order + 1 + 2 * i;                      // -5,-3,-1,1,3,5
    p[i] = -std::exp(std::complex<double>(0.0, M_PI * m / (2.0 * order)));
  }
  std::complex<double> prod1(1, 0);
  for (int i = 0; i < 6; i++) prod1 *= -p[i];
  double k = (1.0 / prod1).real();
  for (int i = 0; i < 6; i++) p[i] = warped / p[i];
  const double fs2 = 2.0 * fs;
  std::complex<double> num(1, 0), den(1, 0);
  for (int i = 0; i < 6; i++) { num *= fs2; den *= (fs2 - p[i]); }
  k *= (num / den).real();
  for (int i = 0; i < 6; i++) p[i] = (fs2 + p[i]) / (fs2 - p[i]);
  std::complex<double> pp[3]; int n = 0;
  for (int i = 0; i < 6; i++) if (p[i].imag() > 0) pp[n++] = p[i];
  std::stable_sort(pp, pp + 3,
    [](const std::complex<double>& A, const std::complex<double>& B) {
      return std::fabs(std::abs(A) - 1.0) > std::fabs(std::abs(B) - 1.0);
    });
  double sos[3][6];
  for (int s = 0; s < 3; s++) {
    double g = (s == 0) ? k : 1.0;
    sos[s][0] = g; sos[s][1] = -2.0 * g; sos[s][2] = g;
    sos[s][3] = 1.0; sos[s][4] = -2.0 * pp[s].real(); sos[s][5] = std::norm(pp[s]);
  }
  double scale = 1.0;
  for (int s = 0; s < 3; s++) {
    double b0 = sos[s][0], b1 = sos[s][1], b2 = sos[s][2];
    double a1 = sos[s][4], a2 = sos[s][5];
    double det = 1.0 + a1 + a2;                      // det of [[1+a1,-1],[a2,1]]
    double r0 = b1 - a1 * b0, r1 = b2 - a2 * b0;
    double z0 = (r0 + r1) / det;
    double z1 = ((1.0 + a1) * r1 - a2 * r0) / det;
    sa.b0[s] = b0; sa.b1[s] = b1; sa.b2[s] = b2; sa.a1[s] = a1; sa.a2[s] = a2;
    sa.zi0[s] = scale * z0; sa.zi1[s] = scale * z1;
    scale *= (b0 + b1 + b2) / (1.0 + a1 + a2);
  }
}

static double host_step(const FiltArg& c, double z[6], double v) {
  for (int s = 0; s < 3; s++) {
    double y = c.b0[s] * v + z[2 * s];
    z[2 * s]     = c.b1[s] * v - c.a1[s] * y + z[2 * s + 1];
    z[2 * s + 1] = c.b2[s] * v - c.a2[s] * y;
    v = y;
  }
  return v;
}

static void build_filt(FiltArg& c, CorArg& co) {
  design_sos(c);
  // CA[i][j]: output at chunk-step i starting from unit state e_j, zero input
  for (int j = 0; j < 6; j++) {
    double z[6] = {0, 0, 0, 0, 0, 0};
    z[j] = 1.0;
    for (int i = 0; i < 32; i++) co.CA[i * 6 + j] = host_step(c, z, 0.0);
  }
}

// Eigen-decomposition of the zero-input state matrix A (block lower
// triangular, 2x2 pole blocks on the diagonal). For each section pole p:
// upstream components 0; v_s = (1, a1_s+p); downstream from the mode
// equations (p z_j0 = ..., solved 2x2). A32 eigenvalue = p^32.
static void build_eig(const FiltArg& c, EigArg& e) {
  double Pr[36];
  for (int s = 0; s < 3; s++) {
    double a1 = c.a1[s], a2 = c.a2[s];
    std::complex<double> disc = std::sqrt(std::complex<double>(a1 * a1 - 4.0 * a2, 0.0));
    std::complex<double> p = (-a1 + disc) / 2.0;
    if (p.imag() < 0) p = std::conj(p);
    std::complex<double> v[6] = {0, 0, 0, 0, 0, 0};
    v[2 * s] = 1.0;
    v[2 * s + 1] = a1 + p;
    std::complex<double> y = 1.0;                    // y_s in mode = z_s0 = 1
    for (int j = s + 1; j < 3; j++) {
      double b0j = c.b0[j], b1j = c.b1[j], b2j = c.b2[j];
      double a1j = c.a1[j], a2j = c.a2[j];
      std::complex<double> det = p * p + a1j * p + a2j;
      std::complex<double> r0 = (b1j - a1j * b0j) * y;
      std::complex<double> r1 = (b2j - a2j * b0j) * y;
      std::complex<double> z0 = (p * r0 + r1) / det;
      std::complex<double> z1 = ((p + a1j) * r1 - a2j * r0) / det;
      v[2 * j] = z0; v[2 * j + 1] = z1;
      y = b0j * y + z0;
    }
    for (int i = 0; i < 6; i++) {
      Pr[i * 6 + 2 * s]     = v[i].real();
      Pr[i * 6 + 2 * s + 1] = v[i].imag();
    }
    std::complex<double> lam = std::pow(p, 32);
    e.lam_re[s] = lam.real(); e.lam_im[s] = lam.imag();
    std::complex<double> li = 1.0 / lam;
    e.lami_re[s] = li.real(); e.lami_im[s] = li.imag();
  }
  for (int i = 0; i < 36; i++) e.Pm[i] = Pr[i];
  // Gauss-Jordan inverse with partial pivoting
  double M[6][12];
  for (int i = 0; i < 6; i++)
    for (int j = 0; j < 6; j++) { M[i][j] = Pr[i * 6 + j]; M[i][6 + j] = (i == j) ? 1.0 : 0.0; }
  for (int col = 0; col < 6; col++) {
    int piv = col;
    for (int i = col + 1; i < 6; i++)
      if (std::fabs(M[i][col]) > std::fabs(M[piv][col])) piv = i;
    if (piv != col) for (int j = 0; j < 12; j++) std::swap(M[col][j], M[piv][j]);
    double d = M[col][col];
    for (int j = 0; j < 12; j++) M[col][j] /= d;
    for (int i = 0; i < 6; i++) if (i != col) {
      double f = M[i][col];
      for (int j = 0; j < 12; j++) M[i][j] -= f * M[col][j];
    }
  }
  for (int i = 0; i < 6; i++)
    for (int j = 0; j < 6; j++) e.Pinv[i * 6 + j] = M[i][6 + j];
  double zv[6];
  for (int s = 0; s < 3; s++) { zv[2 * s] = c.zi0[s]; zv[2 * s + 1] = c.zi1[s]; }
  for (int i = 0; i < 6; i++) {
    double sum = 0.0;
    for (int j = 0; j < 6; j++) sum += e.Pinv[i * 6 + j] * zv[j];
    e.czi[i] = sum;
  }
}

static double bessel_i0(double x) {
  double s = 1.0, t = 1.0;
  for (int k = 1; k < 64; k++) {
    double u = x / (2.0 * k);
    t *= u * u; s += t;
    if (t < 1e-18 * s) break;
  }
  return s;
}

static void design_fir(FirArg& fa) {
  double h[501];
  const double fc = 1.0 / 25.0;
  double denom = bessel_i0(5.0);
  double sum = 0.0;
  for (int nn = 0; nn < 501; nn++) {
    double m = nn - 250.0;
    double xx = fc * m;
    double snc = (nn == 250) ? 1.0 : std::sin(M_PI * xx) / (M_PI * xx);
    double r = (2.0 * nn) / 500.0 - 1.0;
    double w = bessel_i0(5.0 * std::sqrt(std::max(0.0, 1.0 - r * r))) / denom;
    h[nn] = fc * snc * w; sum += h[nn];
  }
  for (int nn = 0; nn < 25; nn++) fa.h[nn] = 0.0f;          // n_pre_pad = 25
  for (int nn = 0; nn < 501; nn++) fa.h[25 + nn] = (float)(h[nn] / sum * 16.0);
}

// ---------------- device helpers ----------------
__device__ inline double waveReduceSum(double v) {
  #pragma unroll
  for (int off = 32; off > 0; off >>= 1) v += __shfl_down(v, off, 64);
  return v;
}

// complex integer power by repeated squaring (n in [0,63])
__device__ inline void cpow_int(double br, double bi, int n, double& rr_, double& ri_) {
  double rr = 1.0, ri = 0.0;
  while (n) {
    if (n & 1) { double t = rr * br - ri * bi; ri = rr * bi + ri * br; rr = t; }
    double t2 = br * br - bi * bi; bi = 2.0 * br * bi; br = t2;
    n >>= 1;
  }
  rr_ = rr; ri_ = ri;
}

// ---------------- kernel 1: chansel + demean, PE table, out-zero (merged) -----
__global__ __launch_bounds__(256) void k_chansel_pe(const float* __restrict__ x,
                                                    float* __restrict__ xs,
                                                    float* __restrict__ pe,
                                                    float* __restrict__ out) {
  int gid = blockIdx.x;
  if (gid < 500) {
    int idx = gid * 256 + threadIdx.x;
    int b = idx / 2000, t = idx % 2000;
    const int ch[10] = {126, 125, 48, 112, 67, 93, 10, 61, 39, 108};
    const float* xb = x + (size_t)b * 128 * 2000;
    float v[10]; float s = 0.f;
    #pragma unroll
    for (int c = 0; c < 10; c++) { v[c] = xb[ch[c] * 2000 + t]; s += v[c]; }
    s *= 0.1f;
    #pragma unroll
    for (int c = 0; c < 10; c++) xs[((size_t)b * 10 + c) * 2000 + t] = v[c] - s;
  } else {
    int i = (gid - 500) * 256 + threadIdx.x;    // [0, 20480)
    int t = i >> 4, d = i & 15, j = d >> 1;
    double div = exp(-((double)(2 * j)) * 0.5756462732485114); // ln(10000)/16
    double a = (double)t * div;
    pe[i] = (float)((d & 1) ? cos(a) : sin(a));
    if (gid == 579 && threadIdx.x < 64) out[threadIdx.x] = 0.f;
  }
}

// ---------------- kernel 2: filtfilt, register pass + log-depth eigen scan ----
// y_true[i] = y_zero[i] + CA[i].z_start (exact). z_start now from the
// CLOSED FORM in eigen-coordinates: c_k = l^k c0 + l^{k-1} sum_{j<k} l^{-j} g_j
// (g = Pinv.F), i.e. a 6-step shfl_up prefix sum -- the two 64-iteration
// serial cross-lane scans (measured ~10us of the 43.5) are gone, and so are
// the Fs/Zs LDS arrays.
#define XR(t) xr[(t) + ((t) >> 5)]
#define YF(t) yf[(t) + ((t) >> 5)]
__global__ __launch_bounds__(64) void k_filtfilt(float* __restrict__ xs,
                                                 FiltArg c, CorArg co, EigArg eg) {
  __shared__ float xr[2112];      // extended input seq (padded)
  __shared__ double yf[2112];     // corrected forward output (padded)
  int r = blockIdx.x;
  int k = threadIdx.x;
  float* x = xs + (size_t)r * 2000;

  float x0f = x[0], xlf = x[1999];
  for (int t = k; t < 2048; t += 64) {
    float v;
    if (t < 21)        v = 2.f * x0f - x[21 - t];
    else if (t < 2021) v = x[t - 21];
    else if (t < 2042) v = 2.f * xlf - x[4019 - t];
    else               v = 0.f;
    XR(t) = v;
  }
  __syncthreads();

  double b0[3], b1[3], b2[3], a1[3], a2[3];
  #pragma unroll
  for (int s = 0; s < 3; s++) {
    b0[s] = c.b0[s]; b1[s] = c.b1[s]; b2[s] = c.b2[s];
    a1[s] = c.a1[s]; a2[s] = c.a2[s];
  }
  auto step = [&](double* z, double v) -> double {
    #pragma unroll
    for (int s = 0; s < 3; s++) {
      double y = b0[s] * v + z[2 * s];
      z[2 * s]     = b1[s] * v - a1[s] * y + z[2 * s + 1];
      z[2 * s + 1] = b2[s] * v - a2[s] * y;
      v = y;
    }
    return v;
  };

  // closed-form chunk-entry state: F = this lane's zero-state final; all
  // register + shfl, no serial iterations.
  auto eigscan = [&](double seed, const double* F, double* zst) {
    double G[6];
    #pragma unroll
    for (int i = 0; i < 6; i++) {
      double s = 0.0;
      #pragma unroll
      for (int j = 0; j < 6; j++) s += eg.Pinv[i * 6 + j] * F[j];
      G[i] = s;
    }
    double coord[6];
    #pragma unroll
    for (int s3 = 0; s3 < 3; s3++) {
      double gre = G[2 * s3], gim = -G[2 * s3 + 1];     // gamma convention: (u, -w)
      double mre, mim;                                  // l^{-k}
      cpow_int(eg.lami_re[s3], eg.lami_im[s3], k, mre, mim);
      double tre = mre * gre - mim * gim;
      double tim = mre * gim + mim * gre;
      double sre = tre, sim = tim;                      // inclusive prefix
      #pragma unroll
      for (int off = 1; off < 64; off <<= 1) {
        double ore = __shfl_up(sre, off, 64);
        double oim = __shfl_up(sim, off, 64);
        sre += (k >= off) ? ore : 0.0;
        sim += (k >= off) ? oim : 0.0;
      }
      double Sre = sre - tre, Sim = sim - tim;          // exclusive prefix
      double c0re = seed * eg.czi[2 * s3];
      double c0im = -seed * eg.czi[2 * s3 + 1];
      double lkre, lkim;                                // l^k
      cpow_int(eg.lam_re[s3], eg.lam_im[s3], k, lkre, lkim);
      double lm1re = lkre * eg.lami_re[s3] - lkim * eg.lami_im[s3];  // l^{k-1}
      double lm1im = lkre * eg.lami_im[s3] + lkim * eg.lami_re[s3];
      if (k == 0) { lm1re = 0.0; lm1im = 0.0; }
      double cre = lkre * c0re - lkim * c0im + lm1re * Sre - lm1im * Sim;
      double cim = lkre * c0im + lkim * c0re + lm1re * Sim + lm1im * Sre;
      coord[2 * s3] = cre;
      coord[2 * s3 + 1] = -cim;
    }
    #pragma unroll
    for (int i = 0; i < 6; i++) {
      double s = 0.0;
      #pragma unroll
      for (int j = 0; j < 6; j++) s += eg.Pm[i * 6 + j] * coord[j];
      zst[i] = s;
    }
  };

  int t0 = k * 32;
  double z[6], yreg[32], zst[6];

  // ---- forward: zero-state pass (registers) ----
  #pragma unroll
  for (int i = 0; i < 6; i++) z[i] = 0.0;
  for (int i = 0; i < 32; i++) yreg[i] = step(z, (double)XR(t0 + i));
  eigscan((double)XR(0), z, zst);
  for (int i = 0; i < 32; i++) {
    double corr = 0.0;
    #pragma unroll
    for (int j = 0; j < 6; j++) corr += co.CA[i * 6 + j] * zst[j];
    YF(t0 + i) = yreg[i] + corr;
  }
  __syncthreads();

  // ---- backward over reversed yf ----
  auto rin = [&](int j) -> double { return (j <= 2041) ? YF(2041 - j) : 0.0; };
  double seedB = YF(2041);
  #pragma unroll
  for (int i = 0; i < 6; i++) z[i] = 0.0;
  for (int i = 0; i < 32; i++) yreg[i] = step(z, rin(t0 + i));
  eigscan(seedB, z, zst);
  for (int i = 0; i < 32; i++) {
    int j = t0 + i;
    if (j >= 21 && j <= 2020) {
      double corr = 0.0;
      #pragma unroll
      for (int jj = 0; jj < 6; jj++) corr += co.CA[i * 6 + jj] * zst[jj];
      x[2020 - j] = (float)(yreg[i] + corr);   // reversed + trimmed
    }
  }
}

// ---------------- kernel 3: polyphase resample + tanh + per-row normalize ----
__global__ __launch_bounds__(256) void k_resample_norm(const float* __restrict__ xf,
                                                       float* __restrict__ xn,
                                                       FirArg fa) {
  __shared__ float xl[2000];
  __shared__ float hl[526];
  int r = blockIdx.x;                         // 640 rows
  const float* x = xf + (size_t)r * 2000;
  for (int i = threadIdx.x; i < 2000; i += 256) xl[i] = x[i];
  for (int i = threadIdx.x; i < 526; i += 256) hl[i] = fa.h[i];
  __syncthreads();
  float vals[5];
  #pragma unroll
  for (int kk = 0; kk < 5; kk++) {
    int o = threadIdx.x + kk * 256;           // 1280 outputs per row
    int P = 25 * (o + 11);
    int phase = P & 15;
    float acc = 0.f;
    for (int m = phase; m <= 525; m += 16) {
      int idx = (P - m) >> 4;
      if (idx >= 0 && idx < 2000) acc += hl[m] * xl[idx];
    }
    vals[kk] = tanhf(acc);
  }
  double s = 0.0, ss = 0.0;
  #pragma unroll
  for (int kk = 0; kk < 5; kk++) {
    s += (double)vals[kk]; ss += (double)vals[kk] * (double)vals[kk];
  }
  s = waveReduceSum(s); ss = waveReduceSum(ss);
  __shared__ double red[8];
  int wid = threadIdx.x >> 6, lane = threadIdx.x & 63;
  if (lane == 0) { red[wid] = s; red[4 + wid] = ss; }
  __syncthreads();
  double S = red[0] + red[1] + red[2] + red[3];
  double SS = red[4] + red[5] + red[6] + red[7];
  double mean = S / 1280.0;
  double var = (SS - 1280.0 * mean * mean) / 1279.0;
  double sd = fmax(sqrt(fmax(var, 0.0)), 1e-6);
  float fmean = (float)mean, finv = (float)(1.0 / sd);
  #pragma unroll
  for (int kk = 0; kk < 5; kk++)
    xn[(size_t)r * 1280 + threadIdx.x + kk * 256] = (vals[kk] - fmean) * finv;
}

// ---------------- kernel 4: conv1d + relu + LN + PE(table) + QKV (fused) ------
__global__ __launch_bounds__(256) void k_conv_ln_pe_qkv(const float* __restrict__ xn,
    const float* __restrict__ cw, const float* __restrict__ cb,
    const float* __restrict__ g0, const float* __restrict__ bt0,
    const float* __restrict__ wqkv, const float* __restrict__ bqkv,
    const float* __restrict__ pe,
    float* __restrict__ x0,
    float* __restrict__ Q, float* __restrict__ K, float* __restrict__ V) {
  __shared__ float w[480], bias[16], gg[16], gb[16];
  __shared__ float wq[768], bq[48];
  for (int i = threadIdx.x; i < 480; i += 256) w[i] = cw[i];
  for (int i = threadIdx.x; i < 768; i += 256) wq[i] = wqkv[i];
  if (threadIdx.x < 16) {
    bias[threadIdx.x] = cb[threadIdx.x];
    gg[threadIdx.x] = g0[threadIdx.x];
    gb[threadIdx.x] = bt0[threadIdx.x];
  }
  if (threadIdx.x < 48) bq[threadIdx.x] = bqkv[threadIdx.x];
  __syncthreads();
  int idx = blockIdx.x * 256 + threadIdx.x;
  int b = idx / 1280, t = idx % 1280;
  const float* xb = xn + (size_t)b * 10 * 1280;
  float in[10][3];
  #pragma unroll
  for (int i = 0; i < 10; i++)
    #pragma unroll
    for (int k = 0; k < 3; k++) {
      int tt = t - 1 + k;
      in[i][k] = (tt >= 0 && tt < 1280) ? xb[i * 1280 + tt] : 0.f;
    }
  float o[16];
  #pragma unroll
  for (int oc = 0; oc < 16; oc++) {
    float a = bias[oc];
    #pragma unroll
    for (int i = 0; i < 10; i++)
      #pragma unroll
      for (int k = 0; k < 3; k++) a += in[i][k] * w[oc * 30 + i * 3 + k];
    o[oc] = fmaxf(a, 0.f);
  }
  float mu = 0.f;
  #pragma unroll
  for (int d = 0; d < 16; d++) mu += o[d];
  mu *= (1.f / 16.f);
  float var = 0.f;
  #pragma unroll
  for (int d = 0; d < 16; d++) { float dd = o[d] - mu; var += dd * dd; }
  var *= (1.f / 16.f);
  float inv = 1.f / sqrtf(var + 1e-5f);
  float xv[16];
  float* outp = x0 + (size_t)idx * 16;
  const float* pep = pe + t * 16;
  #pragma unroll
  for (int d = 0; d < 16; d++) {
    xv[d] = (o[d] - mu) * inv * gg[d] + gb[d] + pep[d];
    outp[d] = xv[d];
  }
  float* qp = Q + (size_t)idx * 16;
  float* kp = K + (size_t)idx * 16;
  float* vp = V + (size_t)idx * 16;
  #pragma unroll
  for (int j = 0; j < 16; j++) {
    float a = bq[j];
    #pragma unroll
    for (int d = 0; d < 16; d++) a += xv[d] * wq[j * 16 + d];
    qp[j] = a;
  }
  #pragma unroll
  for (int j = 0; j < 16; j++) {
    float a = bq[16 + j];
    #pragma unroll
    for (int d = 0; d < 16; d++) a += xv[d] * wq[(16 + j) * 16 + d];
    kp[j] = a;
  }
  #pragma unroll
  for (int j = 0; j < 16; j++) {
    float a = bq[32 + j];
    #pragma unroll
    for (int d = 0; d < 16; d++) a += xv[d] * wq[(32 + j) * 16 + d];
    vp[j] = a;
  }
}

// ---------------- kernel 5: MFMA attention (round-11 measured-best) -----------
#define ATT_SHIFT 12.0f
__global__ __launch_bounds__(256) void k_attn_mfma(const float* __restrict__ Q,
    const float* __restrict__ K, const float* __restrict__ V,
    float* __restrict__ A) {
  __shared__ __align__(16) _Float16 Ks[64 * 40];   // [key][d], d 16..31 zero
  __shared__ __align__(16) _Float16 Vt[16 * 72];   // [d][key]
  __shared__ __align__(16) _Float16 Pld[4][16 * 40]; // per-wave [qrow][key32]
  int tid = threadIdx.x;
  int b  = blockIdx.x / 20;
  int rg = blockIdx.x % 20;
  int wv = tid >> 6;
  int lane = tid & 63;
  int col = lane & 15;
  int quad = lane >> 4;
  size_t base = (size_t)b * 1280;
  int row0 = rg * 64 + wv * 16;

  f16x8 qf;
  #pragma unroll
  for (int j = 0; j < 8; j++) qf[j] = (_Float16)0.f;
  if (quad < 2) {
    const float* qp = Q + (base + row0 + col) * 16 + quad * 8;
    #pragma unroll
    for (int j = 0; j < 8; j++) qf[j] = (_Float16)(0.25f * qp[j]);
  }
  f32x4 oacc = {0.f, 0.f, 0.f, 0.f};
  float lacc = 0.f;

  for (int s = 0; s < 20; s++) {
    __syncthreads();
    {
      int key = tid >> 2, part = tid & 3;
      const float* kp = K + (base + s * 64 + key) * 16 + part * 4;
      f16x4 hk, hz;
      #pragma unroll
      for (int j = 0; j < 4; j++) { hk[j] = (_Float16)kp[j]; hz[j] = (_Float16)0.f; }
      *(f16x4*)&Ks[key * 40 + part * 4] = hk;
      *(f16x4*)&Ks[key * 40 + 16 + part * 4] = hz;
      const float* vp = V + (base + s * 64 + key) * 16 + part * 4;
      #pragma unroll
      for (int j = 0; j < 4; j++) Vt[(part * 4 + j) * 72 + key] = (_Float16)vp[j];
    }
    __syncthreads();
    #pragma unroll
    for (int c = 0; c < 2; c++) {
      #pragma unroll
      for (int t = 0; t < 2; t++) {
        int keyoff = c * 32 + t * 16;
        f16x8 af = *(f16x8*)&Ks[(keyoff + col) * 40 + quad * 8];
        f32x4 sf = {0.f, 0.f, 0.f, 0.f};
        sf = __builtin_amdgcn_mfma_f32_16x16x32_f16(af, qf, sf, 0, 0, 0);
        f16x4 ph;
        float psum = 0.f;
        #pragma unroll
        for (int r = 0; r < 4; r++) {
          float p = __expf(sf[r] - ATT_SHIFT);
          psum += p;
          ph[r] = (_Float16)p;
        }
        lacc += psum;
        *(f16x4*)&Pld[wv][col * 40 + t * 16 + quad * 4] = ph;
      }
      __syncthreads();
      f16x8 pf = *(f16x8*)&Pld[wv][col * 40 + quad * 8];
      f16x8 vf = *(f16x8*)&Vt[col * 72 + c * 32 + quad * 8];
      oacc = __builtin_amdgcn_mfma_f32_16x16x32_f16(pf, vf, oacc, 0, 0, 0);
      __syncthreads();
    }
  }
  lacc += __shfl_xor(lacc, 16, 64);
  lacc += __shfl_xor(lacc, 32, 64);
  #pragma unroll
  for (int r = 0; r < 4; r++) {
    float lr = __shfl(lacc, quad * 4 + r, 64);
    A[(base + row0 + quad * 4 + r) * 16 + col] = oacc[r] / lr;
  }
}

// ---------------- kernel 6: combine + wo + LN1 + FFN + LN2 + pool (fused) -----
__global__ __launch_bounds__(256) void k_combine_pool(
    const float* __restrict__ A, const float* __restrict__ x0,
    const float* __restrict__ wo, const float* __restrict__ bo,
    const float* __restrict__ w1, const float* __restrict__ b1,
    const float* __restrict__ w2, const float* __restrict__ b2,
    const float* __restrict__ g1, const float* __restrict__ bb1,
    const float* __restrict__ g2, const float* __restrict__ bb2,
    const float* __restrict__ wfc, const float* __restrict__ bfc,
    float* __restrict__ out) {
  __shared__ float swo[256], sw1[512], sw2[512];
  __shared__ float sbo[16], sb1[32], sb2[16], sg1[16], sbb1[16], sg2[16], sbb2[16];
  __shared__ float swf[16];
  int tid = threadIdx.x;
  swo[tid] = wo[tid];
  for (int i = tid; i < 512; i += 256) { sw1[i] = w1[i]; sw2[i] = w2[i]; }
  if (tid < 16) {
    sbo[tid] = bo[tid]; sb2[tid] = b2[tid];
    sg1[tid] = g1[tid]; sbb1[tid] = bb1[tid];
    sg2[tid] = g2[tid]; sbb2[tid] = bb2[tid];
    swf[tid] = wfc[tid];
  }
  if (tid < 32) sb1[tid] = b1[tid];
  __syncthreads();

  int idx = blockIdx.x * 256 + tid;          // [0, 81920)
  int bb = blockIdx.x / 5;
  const float* pa = A + (size_t)idx * 16;
  float a[16];
  #pragma unroll
  for (int d = 0; d < 16; d++) a[d] = pa[d];
  float h[16];
  const float* xr = x0 + (size_t)idx * 16;
  #pragma unroll
  for (int d = 0; d < 16; d++) {
    float o = sbo[d];
    #pragma unroll
    for (int e = 0; e < 16; e++) o += a[e] * swo[d * 16 + e];
    h[d] = xr[d] + o;
  }
  float mu = 0.f;
  #pragma unroll
  for (int d = 0; d < 16; d++) mu += h[d];
  mu *= (1.f / 16.f);
  float var = 0.f;
  #pragma unroll
  for (int d = 0; d < 16; d++) { float dd = h[d] - mu; var += dd * dd; }
  var *= (1.f / 16.f);
  float inv = 1.f / sqrtf(var + 1e-5f);
  float x1[16];
  #pragma unroll
  for (int d = 0; d < 16; d++) x1[d] = (h[d] - mu) * inv * sg1[d] + sbb1[d];
  float t1[32];
  #pragma unroll
  for (int j = 0; j < 32; j++) {
    float u = sb1[j];
    #pragma unroll
    for (int d = 0; d < 16; d++) u += x1[d] * sw1[j * 16 + d];
    t1[j] = fmaxf(u, 0.f);
  }
  float h2[16];
  #pragma unroll
  for (int d = 0; d < 16; d++) {
    float u = sb2[d];
    #pragma unroll
    for (int j = 0; j < 32; j++) u += t1[j] * sw2[d * 32 + j];
    h2[d] = x1[d] + u;
  }
  mu = 0.f;
  #pragma unroll
  for (int d = 0; d < 16; d++) mu += h2[d];
  mu *= (1.f / 16.f);
  var = 0.f;
  #pragma unroll
  for (int d = 0; d < 16; d++) { float dd = h2[d] - mu; var += dd * dd; }
  var *= (1.f / 16.f);
  inv = 1.f / sqrtf(var + 1e-5f);
  float pv = 0.f;
  #pragma unroll
  for (int d = 0; d < 16; d++)
    pv += ((h2[d] - mu) * inv * sg2[d] + sbb2[d]) * swf[d];
  double part = waveReduceSum((double)pv);
  __shared__ double red[4];
  int wid = tid >> 6, lane = tid & 63;
  if (lane == 0) red[wid] = part;
  __syncthreads();
  if (tid == 0) {
    double S = red[0] + red[1] + red[2] + red[3];
    float add = (float)(S / 1280.0);
    if (blockIdx.x % 5 == 0) add += bfc[0];
    atomicAdd(&out[bb], add);
  }
}

// ---------------- launch ------------------------------------------------------
extern "C" void kernel_launch(void* const* d_in, const int* in_sizes, int n_in,
                              void* d_out, int out_size, void* d_ws, size_t ws_size,
                              hipStream_t stream) {
  const float* x    = (const float*)d_in[0];
  const float* cw   = (const float*)d_in[1];
  const float* cb   = (const float*)d_in[2];
  const float* g0   = (const float*)d_in[3];
  const float* bt0  = (const float*)d_in[4];
  const float* wqkv = (const float*)d_in[5];
  const float* bqkv = (const float*)d_in[6];
  const float* wo   = (const float*)d_in[7];
  const float* bo   = (const float*)d_in[8];
  const float* w1   = (const float*)d_in[9];
  const float* b1   = (const float*)d_in[10];
  const float* w2   = (const float*)d_in[11];
  const float* b2   = (const float*)d_in[12];
  const float* g1   = (const float*)d_in[13];
  const float* bb1  = (const float*)d_in[14];
  const float* g2   = (const float*)d_in[15];
  const float* bb2  = (const float*)d_in[16];
  const float* wfc  = (const float*)d_in[17];
  const float* bfc  = (const float*)d_in[18];
  float* out = (float*)d_out;

  float* ws = (float*)d_ws;
  float* xs = ws;                       // 640*2000 = 1,280,000 (filtered in-place;
                                        // dead after k_resample_norm -> reused as A)
  float* y1 = xs + 1280000;             // spacer (dead)
  float* xn = y1 + 1306880;             // 640*1280   =   819,200
  float* x0 = xn + 819200;              // 64*1280*16 = 1,310,720
  float* Q  = x0 + 1310720;
  float* Kb = Q  + 1310720;
  float* Vb = Kb + 1310720;
  float* pe = Vb + 1310720;             // 1280*16 = 20,480  (total ~36 MB)
  float* Abuf = ws;                     // attention output (reuses dead xs)

  FiltArg fc; CorArg co; EigArg eg; FirArg fa;
  build_filt(fc, co);
  build_eig(fc, eg);
  design_fir(fa);

  k_chansel_pe<<<580, 256, 0, stream>>>(x, xs, pe, out);
  k_filtfilt<<<640, 64, 0, stream>>>(xs, fc, co, eg);
  k_resample_norm<<<640, 256, 0, stream>>>(xs, xn, fa);
  k_conv_ln_pe_qkv<<<320, 256, 0, stream>>>(xn, cw, cb, g0, bt0, wqkv, bqkv,
                                            pe, x0, Q, Kb, Vb);
  k_attn_mfma<<<1280, 256, 0, stream>>>(Q, Kb, Vb, Abuf);
  k_combine_pool<<<320, 256, 0, stream>>>(Abuf, x0, wo, bo, w1, b1, w2, b2,
                                          g1, bb1, g2, bb2, wfc, bfc, out);
}

// Round 15
// 242.829 us; speedup vs baseline: 1.2223x; 1.0399x over previous
//
#include <hip/hip_runtime.h>
#include <cmath>
#include <complex>
#include <algorithm>

#ifndef M_PI
#define M_PI 3.14159265358979323846
#endif

typedef _Float16 f16x8 __attribute__((ext_vector_type(8)));
typedef _Float16 f16x4 __attribute__((ext_vector_type(4)));
typedef float f32x4 __attribute__((ext_vector_type(4)));

// ---------------- coefficient structs (passed by value as kernel args) ---------
struct FiltArg {
  double b0[3], b1[3], b2[3], a1[3], a2[3];
  double zi0[3], zi1[3];
};
struct CorArg { double CA[16 * 6]; };  // CA[i][j] = output at step i from unit state e_j
struct EigArg {
  double Pm[36], Pinv[36];   // eigenbasis of the single-step state matrix A
  double czi[6];             // Pinv · (zi vector)
  double lam_re[3], lam_im[3];   // λ_s = p_s^16  (chunk = 16 steps)
  double lami_re[3], lami_im[3]; // λ_s^{-1}
};
struct FirArg { float h[526]; };  // 25 leading zeros + 501-tap kaiser-sinc, *UP

// ---------------- host-side filter design (exact replica of reference) --------
static void design_sos(FiltArg& sa) {
  const int order = 6;
  const double wn = 0.5 / 50.0;
  const double fs = 2.0;
  double warped = 2.0 * fs * std::tan(M_PI * wn / fs);
  std::complex<double> p[6];
  for (int i = 0; i < order; i++) {
    int m = -order + 1 + 2 * i;                      // -5,-3,-1,1,3,5
    p[i] = -std::exp(std::complex<double>(0.0, M_PI * m / (2.0 * order)));
  }
  std::complex<double> prod1(1, 0);
  for (int i = 0; i < 6; i++) prod1 *= -p[i];
  double k = (1.0 / prod1).real();
  for (int i = 0; i < 6; i++) p[i] = warped / p[i];
  const double fs2 = 2.0 * fs;
  std::complex<double> num(1, 0), den(1, 0);
  for (int i = 0; i < 6; i++) { num *= fs2; den *= (fs2 - p[i]); }
  k *= (num / den).real();
  for (int i = 0; i < 6; i++) p[i] = (fs2 + p[i]) / (fs2 - p[i]);
  std::complex<double> pp[3]; int n = 0;
  for (int i = 0; i < 6; i++) if (p[i].imag() > 0) pp[n++] = p[i];
  std::stable_sort(pp, pp + 3,
    [](const std::complex<double>& A, const std::complex<double>& B) {
      return std::fabs(std::abs(A) - 1.0) > std::fabs(std::abs(B) - 1.0);
    });
  double sos[3][6];
  for (int s = 0; s < 3; s++) {
    double g = (s == 0) ? k : 1.0;
    sos[s][0] = g; sos[s][1] = -2.0 * g; sos[s][2] = g;
    sos[s][3] = 1.0; sos[s][4] = -2.0 * pp[s].real(); sos[s][5] = std::norm(pp[s]);
  }
  double scale = 1.0;
  for (int s = 0; s < 3; s++) {
    double b0 = sos[s][0], b1 = sos[s][1], b2 = sos[s][2];
    double a1 = sos[s][4], a2 = sos[s][5];
    double det = 1.0 + a1 + a2;                      // det of [[1+a1,-1],[a2,1]]
    double r0 = b1 - a1 * b0, r1 = b2 - a2 * b0;
    double z0 = (r0 + r1) / det;
    double z1 = ((1.0 + a1) * r1 - a2 * r0) / det;
    sa.b0[s] = b0; sa.b1[s] = b1; sa.b2[s] = b2; sa.a1[s] = a1; sa.a2[s] = a2;
    sa.zi0[s] = scale * z0; sa.zi1[s] = scale * z1;
    scale *= (b0 + b1 + b2) / (1.0 + a1 + a2);
  }
}

static double host_step(const FiltArg& c, double z[6], double v) {
  for (int s = 0; s < 3; s++) {
    double y = c.b0[s] * v + z[2 * s];
    z[2 * s]     = c.b1[s] * v - c.a1[s] * y + z[2 * s + 1];
    z[2 * s + 1] = c.b2[s] * v - c.a2[s] * y;
    v = y;
  }
  return v;
}

static void build_filt(FiltArg& c, CorArg& co) {
  design_sos(c);
  // CA[i][j]: output at chunk-step i starting from unit state e_j, zero input
  for (int j = 0; j < 6; j++) {
    double z[6] = {0, 0, 0, 0, 0, 0};
    z[j] = 1.0;
    for (int i = 0; i < 16; i++) co.CA[i * 6 + j] = host_step(c, z, 0.0);
  }
}

// Eigen-decomposition of the zero-input single-step state matrix A (block
// lower triangular, 2x2 pole blocks). Chunk transition = A^16 shares the
// eigenvectors; eigenvalue = p^16.
static void build_eig(const FiltArg& c, EigArg& e) {
  double Pr[36];
  for (int s = 0; s < 3; s++) {
    double a1 = c.a1[s], a2 = c.a2[s];
    std::complex<double> disc = std::sqrt(std::complex<double>(a1 * a1 - 4.0 * a2, 0.0));
    std::complex<double> p = (-a1 + disc) / 2.0;
    if (p.imag() < 0) p = std::conj(p);
    std::complex<double> v[6] = {0, 0, 0, 0, 0, 0};
    v[2 * s] = 1.0;
    v[2 * s + 1] = a1 + p;
    std::complex<double> y = 1.0;
    for (int j = s + 1; j < 3; j++) {
      double b0j = c.b0[j], b1j = c.b1[j], b2j = c.b2[j];
      double a1j = c.a1[j], a2j = c.a2[j];
      std::complex<double> det = p * p + a1j * p + a2j;
      std::complex<double> r0 = (b1j - a1j * b0j) * y;
      std::complex<double> r1 = (b2j - a2j * b0j) * y;
      std::complex<double> z0 = (p * r0 + r1) / det;
      std::complex<double> z1 = ((p + a1j) * r1 - a2j * r0) / det;
      v[2 * j] = z0; v[2 * j + 1] = z1;
      y = b0j * y + z0;
    }
    for (int i = 0; i < 6; i++) {
      Pr[i * 6 + 2 * s]     = v[i].real();
      Pr[i * 6 + 2 * s + 1] = v[i].imag();
    }
    std::complex<double> lam = std::pow(p, 16);
    e.lam_re[s] = lam.real(); e.lam_im[s] = lam.imag();
    std::complex<double> li = 1.0 / lam;
    e.lami_re[s] = li.real(); e.lami_im[s] = li.imag();
  }
  for (int i = 0; i < 36; i++) e.Pm[i] = Pr[i];
  double M[6][12];
  for (int i = 0; i < 6; i++)
    for (int j = 0; j < 6; j++) { M[i][j] = Pr[i * 6 + j]; M[i][6 + j] = (i == j) ? 1.0 : 0.0; }
  for (int col = 0; col < 6; col++) {
    int piv = col;
    for (int i = col + 1; i < 6; i++)
      if (std::fabs(M[i][col]) > std::fabs(M[piv][col])) piv = i;
    if (piv != col) for (int j = 0; j < 12; j++) std::swap(M[col][j], M[piv][j]);
    double d = M[col][col];
    for (int j = 0; j < 12; j++) M[col][j] /= d;
    for (int i = 0; i < 6; i++) if (i != col) {
      double f = M[i][col];
      for (int j = 0; j < 12; j++) M[i][j] -= f * M[col][j];
    }
  }
  for (int i = 0; i < 6; i++)
    for (int j = 0; j < 6; j++) e.Pinv[i * 6 + j] = M[i][6 + j];
  double zv[6];
  for (int s = 0; s < 3; s++) { zv[2 * s] = c.zi0[s]; zv[2 * s + 1] = c.zi1[s]; }
  for (int i = 0; i < 6; i++) {
    double sum = 0.0;
    for (int j = 0; j < 6; j++) sum += e.Pinv[i * 6 + j] * zv[j];
    e.czi[i] = sum;
  }
}

static double bessel_i0(double x) {
  double s = 1.0, t = 1.0;
  for (int k = 1; k < 64; k++) {
    double u = x / (2.0 * k);
    t *= u * u; s += t;
    if (t < 1e-18 * s) break;
  }
  return s;
}

static void design_fir(FirArg& fa) {
  double h[501];
  const double fc = 1.0 / 25.0;
  double denom = bessel_i0(5.0);
  double sum = 0.0;
  for (int nn = 0; nn < 501; nn++) {
    double m = nn - 250.0;
    double xx = fc * m;
    double snc = (nn == 250) ? 1.0 : std::sin(M_PI * xx) / (M_PI * xx);
    double r = (2.0 * nn) / 500.0 - 1.0;
    double w = bessel_i0(5.0 * std::sqrt(std::max(0.0, 1.0 - r * r))) / denom;
    h[nn] = fc * snc * w; sum += h[nn];
  }
  for (int nn = 0; nn < 25; nn++) fa.h[nn] = 0.0f;          // n_pre_pad = 25
  for (int nn = 0; nn < 501; nn++) fa.h[25 + nn] = (float)(h[nn] / sum * 16.0);
}

// ---------------- device helpers ----------------
__device__ inline double waveReduceSum(double v) {
  #pragma unroll
  for (int off = 32; off > 0; off >>= 1) v += __shfl_down(v, off, 64);
  return v;
}

// complex integer power by repeated squaring (n in [0,127])
__device__ inline void cpow_int(double br, double bi, int n, double& rr_, double& ri_) {
  double rr = 1.0, ri = 0.0;
  while (n) {
    if (n & 1) { double t = rr * br - ri * bi; ri = rr * bi + ri * br; rr = t; }
    double t2 = br * br - bi * bi; bi = 2.0 * br * bi; br = t2;
    n >>= 1;
  }
  rr_ = rr; ri_ = ri;
}

// ---------------- kernel 1: chansel + demean, PE table, out-zero (merged) -----
__global__ __launch_bounds__(256) void k_chansel_pe(const float* __restrict__ x,
                                                    float* __restrict__ xs,
                                                    float* __restrict__ pe,
                                                    float* __restrict__ out) {
  int gid = blockIdx.x;
  if (gid < 500) {
    int idx = gid * 256 + threadIdx.x;
    int b = idx / 2000, t = idx % 2000;
    const int ch[10] = {126, 125, 48, 112, 67, 93, 10, 61, 39, 108};
    const float* xb = x + (size_t)b * 128 * 2000;
    float v[10]; float s = 0.f;
    #pragma unroll
    for (int c = 0; c < 10; c++) { v[c] = xb[ch[c] * 2000 + t]; s += v[c]; }
    s *= 0.1f;
    #pragma unroll
    for (int c = 0; c < 10; c++) xs[((size_t)b * 10 + c) * 2000 + t] = v[c] - s;
  } else {
    int i = (gid - 500) * 256 + threadIdx.x;    // [0, 20480)
    int t = i >> 4, d = i & 15, j = d >> 1;
    double div = exp(-((double)(2 * j)) * 0.5756462732485114); // ln(10000)/16
    double a = (double)t * div;
    pe[i] = (float)((d & 1) ? cos(a) : sin(a));
    if (gid == 579 && threadIdx.x < 64) out[threadIdx.x] = 0.f;
  }
}

// ---------------- kernel 2: filtfilt, 128 chunks x 16 steps, eigen prefix -----
// Block = 128 threads (2 waves) per row. Serial dependent chain halved vs the
// 64x32 layout (round 14: 41us); closed-form chunk-entry states via
// wave-local shfl_up prefix + one LDS cross-wave handoff. λ = p^16.
#define XR(t) xr[(t) + ((t) >> 5)]
#define YF(t) yf[(t) + ((t) >> 5)]
__global__ __launch_bounds__(128) void k_filtfilt(float* __restrict__ xs,
                                                  FiltArg c, CorArg co, EigArg eg) {
  __shared__ float xr[2112];      // extended input seq (padded)
  __shared__ double yf[2112];     // corrected forward output (padded)
  __shared__ double wsum[3][2];   // wave0 inclusive totals per section
  int r = blockIdx.x;
  int gk = threadIdx.x;           // global chunk id 0..127
  int lane = gk & 63;
  int wv = gk >> 6;
  float* x = xs + (size_t)r * 2000;

  float x0f = x[0], xlf = x[1999];
  for (int t = gk; t < 2048; t += 128) {
    float v;
    if (t < 21)        v = 2.f * x0f - x[21 - t];
    else if (t < 2021) v = x[t - 21];
    else if (t < 2042) v = 2.f * xlf - x[4019 - t];
    else               v = 0.f;
    XR(t) = v;
  }
  __syncthreads();

  double b0[3], b1[3], b2[3], a1[3], a2[3];
  #pragma unroll
  for (int s = 0; s < 3; s++) {
    b0[s] = c.b0[s]; b1[s] = c.b1[s]; b2[s] = c.b2[s];
    a1[s] = c.a1[s]; a2[s] = c.a2[s];
  }
  auto step = [&](double* z, double v) -> double {
    #pragma unroll
    for (int s = 0; s < 3; s++) {
      double y = b0[s] * v + z[2 * s];
      z[2 * s]     = b1[s] * v - a1[s] * y + z[2 * s + 1];
      z[2 * s + 1] = b2[s] * v - a2[s] * y;
      v = y;
    }
    return v;
  };

  // closed-form chunk-entry state via 128-lane weighted prefix:
  // c_k = λ^k c0 + λ^{k-1} Σ_{j<k} λ^{-j} g_j ; g = Pinv·F
  auto eigscan = [&](double seed, const double* F, double* zst) {
    double G[6];
    #pragma unroll
    for (int i = 0; i < 6; i++) {
      double s = 0.0;
      #pragma unroll
      for (int j = 0; j < 6; j++) s += eg.Pinv[i * 6 + j] * F[j];
      G[i] = s;
    }
    double tre[3], tim[3], sre[3], sim[3];
    #pragma unroll
    for (int s3 = 0; s3 < 3; s3++) {
      double gre = G[2 * s3], gim = -G[2 * s3 + 1];
      double mre, mim;                                  // λ^{-gk}
      cpow_int(eg.lami_re[s3], eg.lami_im[s3], gk, mre, mim);
      tre[s3] = mre * gre - mim * gim;
      tim[s3] = mre * gim + mim * gre;
      double pr = tre[s3], pi = tim[s3];                // wave-local inclusive
      #pragma unroll
      for (int off = 1; off < 64; off <<= 1) {
        double ore = __shfl_up(pr, off, 64);
        double oim = __shfl_up(pi, off, 64);
        pr += (lane >= off) ? ore : 0.0;
        pi += (lane >= off) ? oim : 0.0;
      }
      sre[s3] = pr; sim[s3] = pi;
      if (wv == 0 && lane == 63) { wsum[s3][0] = pr; wsum[s3][1] = pi; }
    }
    __syncthreads();
    double coord[6];
    #pragma unroll
    for (int s3 = 0; s3 < 3; s3++) {
      double inc_re = sre[s3] + (wv ? wsum[s3][0] : 0.0);
      double inc_im = sim[s3] + (wv ? wsum[s3][1] : 0.0);
      double Sre = inc_re - tre[s3], Sim = inc_im - tim[s3];  // exclusive
      double c0re = seed * eg.czi[2 * s3];
      double c0im = -seed * eg.czi[2 * s3 + 1];
      double lkre, lkim;                                // λ^{gk}
      cpow_int(eg.lam_re[s3], eg.lam_im[s3], gk, lkre, lkim);
      double lm1re = lkre * eg.lami_re[s3] - lkim * eg.lami_im[s3];  // λ^{gk-1}
      double lm1im = lkre * eg.lami_im[s3] + lkim * eg.lami_re[s3];
      if (gk == 0) { lm1re = 0.0; lm1im = 0.0; }
      double cre = lkre * c0re - lkim * c0im + lm1re * Sre - lm1im * Sim;
      double cim = lkre * c0im + lkim * c0re + lm1re * Sim + lm1im * Sre;
      coord[2 * s3] = cre;
      coord[2 * s3 + 1] = -cim;
    }
    #pragma unroll
    for (int i = 0; i < 6; i++) {
      double s = 0.0;
      #pragma unroll
      for (int j = 0; j < 6; j++) s += eg.Pm[i * 6 + j] * coord[j];
      zst[i] = s;
    }
  };

  int t0 = gk * 16;
  double z[6], yreg[16], zst[6];

  // ---- forward: zero-state pass (registers) ----
  #pragma unroll
  for (int i = 0; i < 6; i++) z[i] = 0.0;
  for (int i = 0; i < 16; i++) yreg[i] = step(z, (double)XR(t0 + i));
  eigscan((double)XR(0), z, zst);
  for (int i = 0; i < 16; i++) {
    double corr = 0.0;
    #pragma unroll
    for (int j = 0; j < 6; j++) corr += co.CA[i * 6 + j] * zst[j];
    YF(t0 + i) = yreg[i] + corr;
  }
  __syncthreads();

  // ---- backward over reversed yf ----
  auto rin = [&](int j) -> double { return (j <= 2041) ? YF(2041 - j) : 0.0; };
  double seedB = YF(2041);
  #pragma unroll
  for (int i = 0; i < 6; i++) z[i] = 0.0;
  for (int i = 0; i < 16; i++) yreg[i] = step(z, rin(t0 + i));
  eigscan(seedB, z, zst);
  for (int i = 0; i < 16; i++) {
    int j = t0 + i;
    if (j >= 21 && j <= 2020) {
      double corr = 0.0;
      #pragma unroll
      for (int jj = 0; jj < 6; jj++) corr += co.CA[i * 6 + jj] * zst[jj];
      x[2020 - j] = (float)(yreg[i] + corr);   // reversed + trimmed
    }
  }
}

// ---------------- kernel 3: polyphase resample + tanh + per-row normalize ----
__global__ __launch_bounds__(256) void k_resample_norm(const float* __restrict__ xf,
                                                       float* __restrict__ xn,
                                                       FirArg fa) {
  __shared__ float xl[2000];
  __shared__ float hl[526];
  int r = blockIdx.x;                         // 640 rows
  const float* x = xf + (size_t)r * 2000;
  for (int i = threadIdx.x; i < 2000; i += 256) xl[i] = x[i];
  for (int i = threadIdx.x; i < 526; i += 256) hl[i] = fa.h[i];
  __syncthreads();
  float vals[5];
  #pragma unroll
  for (int kk = 0; kk < 5; kk++) {
    int o = threadIdx.x + kk * 256;           // 1280 outputs per row
    int P = 25 * (o + 11);
    int phase = P & 15;
    float acc = 0.f;
    for (int m = phase; m <= 525; m += 16) {
      int idx = (P - m) >> 4;
      if (idx >= 0 && idx < 2000) acc += hl[m] * xl[idx];
    }
    vals[kk] = tanhf(acc);
  }
  double s = 0.0, ss = 0.0;
  #pragma unroll
  for (int kk = 0; kk < 5; kk++) {
    s += (double)vals[kk]; ss += (double)vals[kk] * (double)vals[kk];
  }
  s = waveReduceSum(s); ss = waveReduceSum(ss);
  __shared__ double red[8];
  int wid = threadIdx.x >> 6, lane = threadIdx.x & 63;
  if (lane == 0) { red[wid] = s; red[4 + wid] = ss; }
  __syncthreads();
  double S = red[0] + red[1] + red[2] + red[3];
  double SS = red[4] + red[5] + red[6] + red[7];
  double mean = S / 1280.0;
  double var = (SS - 1280.0 * mean * mean) / 1279.0;
  double sd = fmax(sqrt(fmax(var, 0.0)), 1e-6);
  float fmean = (float)mean, finv = (float)(1.0 / sd);
  #pragma unroll
  for (int kk = 0; kk < 5; kk++)
    xn[(size_t)r * 1280 + threadIdx.x + kk * 256] = (vals[kk] - fmean) * finv;
}

// ---------------- kernel 4: conv1d + relu + LN + PE(table) + QKV (fused) ------
__global__ __launch_bounds__(256) void k_conv_ln_pe_qkv(const float* __restrict__ xn,
    const float* __restrict__ cw, const float* __restrict__ cb,
    const float* __restrict__ g0, const float* __restrict__ bt0,
    const float* __restrict__ wqkv, const float* __restrict__ bqkv,
    const float* __restrict__ pe,
    float* __restrict__ x0,
    float* __restrict__ Q, float* __restrict__ K, float* __restrict__ V) {
  __shared__ float w[480], bias[16], gg[16], gb[16];
  __shared__ float wq[768], bq[48];
  for (int i = threadIdx.x; i < 480; i += 256) w[i] = cw[i];
  for (int i = threadIdx.x; i < 768; i += 256) wq[i] = wqkv[i];
  if (threadIdx.x < 16) {
    bias[threadIdx.x] = cb[threadIdx.x];
    gg[threadIdx.x] = g0[threadIdx.x];
    gb[threadIdx.x] = bt0[threadIdx.x];
  }
  if (threadIdx.x < 48) bq[threadIdx.x] = bqkv[threadIdx.x];
  __syncthreads();
  int idx = blockIdx.x * 256 + threadIdx.x;
  int b = idx / 1280, t = idx % 1280;
  const float* xb = xn + (size_t)b * 10 * 1280;
  float in[10][3];
  #pragma unroll
  for (int i = 0; i < 10; i++)
    #pragma unroll
    for (int k = 0; k < 3; k++) {
      int tt = t - 1 + k;
      in[i][k] = (tt >= 0 && tt < 1280) ? xb[i * 1280 + tt] : 0.f;
    }
  float o[16];
  #pragma unroll
  for (int oc = 0; oc < 16; oc++) {
    float a = bias[oc];
    #pragma unroll
    for (int i = 0; i < 10; i++)
      #pragma unroll
      for (int k = 0; k < 3; k++) a += in[i][k] * w[oc * 30 + i * 3 + k];
    o[oc] = fmaxf(a, 0.f);
  }
  float mu = 0.f;
  #pragma unroll
  for (int d = 0; d < 16; d++) mu += o[d];
  mu *= (1.f / 16.f);
  float var = 0.f;
  #pragma unroll
  for (int d = 0; d < 16; d++) { float dd = o[d] - mu; var += dd * dd; }
  var *= (1.f / 16.f);
  float inv = 1.f / sqrtf(var + 1e-5f);
  float xv[16];
  float* outp = x0 + (size_t)idx * 16;
  const float* pep = pe + t * 16;
  #pragma unroll
  for (int d = 0; d < 16; d++) {
    xv[d] = (o[d] - mu) * inv * gg[d] + gb[d] + pep[d];
    outp[d] = xv[d];
  }
  float* qp = Q + (size_t)idx * 16;
  float* kp = K + (size_t)idx * 16;
  float* vp = V + (size_t)idx * 16;
  #pragma unroll
  for (int j = 0; j < 16; j++) {
    float a = bq[j];
    #pragma unroll
    for (int d = 0; d < 16; d++) a += xv[d] * wq[j * 16 + d];
    qp[j] = a;
  }
  #pragma unroll
  for (int j = 0; j < 16; j++) {
    float a = bq[16 + j];
    #pragma unroll
    for (int d = 0; d < 16; d++) a += xv[d] * wq[(16 + j) * 16 + d];
    kp[j] = a;
  }
  #pragma unroll
  for (int j = 0; j < 16; j++) {
    float a = bq[32 + j];
    #pragma unroll
    for (int d = 0; d < 16; d++) a += xv[d] * wq[(32 + j) * 16 + d];
    vp[j] = a;
  }
}

// ---------------- kernel 5: MFMA attention (round-11 measured-best) -----------
#define ATT_SHIFT 12.0f
__global__ __launch_bounds__(256) void k_attn_mfma(const float* __restrict__ Q,
    const float* __restrict__ K, const float* __restrict__ V,
    float* __restrict__ A) {
  __shared__ __align__(16) _Float16 Ks[64 * 40];   // [key][d], d 16..31 zero
  __shared__ __align__(16) _Float16 Vt[16 * 72];   // [d][key]
  __shared__ __align__(16) _Float16 Pld[4][16 * 40]; // per-wave [qrow][key32]
  int tid = threadIdx.x;
  int b  = blockIdx.x / 20;
  int rg = blockIdx.x % 20;
  int wv = tid >> 6;
  int lane = tid & 63;
  int col = lane & 15;
  int quad = lane >> 4;
  size_t base = (size_t)b * 1280;
  int row0 = rg * 64 + wv * 16;

  f16x8 qf;
  #pragma unroll
  for (int j = 0; j < 8; j++) qf[j] = (_Float16)0.f;
  if (quad < 2) {
    const float* qp = Q + (base + row0 + col) * 16 + quad * 8;
    #pragma unroll
    for (int j = 0; j < 8; j++) qf[j] = (_Float16)(0.25f * qp[j]);
  }
  f32x4 oacc = {0.f, 0.f, 0.f, 0.f};
  float lacc = 0.f;

  for (int s = 0; s < 20; s++) {
    __syncthreads();
    {
      int key = tid >> 2, part = tid & 3;
      const float* kp = K + (base + s * 64 + key) * 16 + part * 4;
      f16x4 hk, hz;
      #pragma unroll
      for (int j = 0; j < 4; j++) { hk[j] = (_Float16)kp[j]; hz[j] = (_Float16)0.f; }
      *(f16x4*)&Ks[key * 40 + part * 4] = hk;
      *(f16x4*)&Ks[key * 40 + 16 + part * 4] = hz;
      const float* vp = V + (base + s * 64 + key) * 16 + part * 4;
      #pragma unroll
      for (int j = 0; j < 4; j++) Vt[(part * 4 + j) * 72 + key] = (_Float16)vp[j];
    }
    __syncthreads();
    #pragma unroll
    for (int c = 0; c < 2; c++) {
      #pragma unroll
      for (int t = 0; t < 2; t++) {
        int keyoff = c * 32 + t * 16;
        f16x8 af = *(f16x8*)&Ks[(keyoff + col) * 40 + quad * 8];
        f32x4 sf = {0.f, 0.f, 0.f, 0.f};
        sf = __builtin_amdgcn_mfma_f32_16x16x32_f16(af, qf, sf, 0, 0, 0);
        f16x4 ph;
        float psum = 0.f;
        #pragma unroll
        for (int r = 0; r < 4; r++) {
          float p = __expf(sf[r] - ATT_SHIFT);
          psum += p;
          ph[r] = (_Float16)p;
        }
        lacc += psum;
        *(f16x4*)&Pld[wv][col * 40 + t * 16 + quad * 4] = ph;
      }
      __syncthreads();
      f16x8 pf = *(f16x8*)&Pld[wv][col * 40 + quad * 8];
      f16x8 vf = *(f16x8*)&Vt[col * 72 + c * 32 + quad * 8];
      oacc = __builtin_amdgcn_mfma_f32_16x16x32_f16(pf, vf, oacc, 0, 0, 0);
      __syncthreads();
    }
  }
  lacc += __shfl_xor(lacc, 16, 64);
  lacc += __shfl_xor(lacc, 32, 64);
  #pragma unroll
  for (int r = 0; r < 4; r++) {
    float lr = __shfl(lacc, quad * 4 + r, 64);
    A[(base + row0 + quad * 4 + r) * 16 + col] = oacc[r] / lr;
  }
}

// ---------------- kernel 6: combine + wo + LN1 + FFN + LN2 + pool (fused) -----
__global__ __launch_bounds__(256) void k_combine_pool(
    const float* __restrict__ A, const float* __restrict__ x0,
    const float* __restrict__ wo, const float* __restrict__ bo,
    const float* __restrict__ w1, const float* __restrict__ b1,
    const float* __restrict__ w2, const float* __restrict__ b2,
    const float* __restrict__ g1, const float* __restrict__ bb1,
    const float* __restrict__ g2, const float* __restrict__ bb2,
    const float* __restrict__ wfc, const float* __restrict__ bfc,
    float* __restrict__ out) {
  __shared__ float swo[256], sw1[512], sw2[512];
  __shared__ float sbo[16], sb1[32], sb2[16], sg1[16], sbb1[16], sg2[16], sbb2[16];
  __shared__ float swf[16];
  int tid = threadIdx.x;
  swo[tid] = wo[tid];
  for (int i = tid; i < 512; i += 256) { sw1[i] = w1[i]; sw2[i] = w2[i]; }
  if (tid < 16) {
    sbo[tid] = bo[tid]; sb2[tid] = b2[tid];
    sg1[tid] = g1[tid]; sbb1[tid] = bb1[tid];
    sg2[tid] = g2[tid]; sbb2[tid] = bb2[tid];
    swf[tid] = wfc[tid];
  }
  if (tid < 32) sb1[tid] = b1[tid];
  __syncthreads();

  int idx = blockIdx.x * 256 + tid;          // [0, 81920)
  int bb = blockIdx.x / 5;
  const float* pa = A + (size_t)idx * 16;
  float a[16];
  #pragma unroll
  for (int d = 0; d < 16; d++) a[d] = pa[d];
  float h[16];
  const float* xr = x0 + (size_t)idx * 16;
  #pragma unroll
  for (int d = 0; d < 16; d++) {
    float o = sbo[d];
    #pragma unroll
    for (int e = 0; e < 16; e++) o += a[e] * swo[d * 16 + e];
    h[d] = xr[d] + o;
  }
  float mu = 0.f;
  #pragma unroll
  for (int d = 0; d < 16; d++) mu += h[d];
  mu *= (1.f / 16.f);
  float var = 0.f;
  #pragma unroll
  for (int d = 0; d < 16; d++) { float dd = h[d] - mu; var += dd * dd; }
  var *= (1.f / 16.f);
  float inv = 1.f / sqrtf(var + 1e-5f);
  float x1[16];
  #pragma unroll
  for (int d = 0; d < 16; d++) x1[d] = (h[d] - mu) * inv * sg1[d] + sbb1[d];
  float t1[32];
  #pragma unroll
  for (int j = 0; j < 32; j++) {
    float u = sb1[j];
    #pragma unroll
    for (int d = 0; d < 16; d++) u += x1[d] * sw1[j * 16 + d];
    t1[j] = fmaxf(u, 0.f);
  }
  float h2[16];
  #pragma unroll
  for (int d = 0; d < 16; d++) {
    float u = sb2[d];
    #pragma unroll
    for (int j = 0; j < 32; j++) u += t1[j] * sw2[d * 32 + j];
    h2[d] = x1[d] + u;
  }
  mu = 0.f;
  #pragma unroll
  for (int d = 0; d < 16; d++) mu += h2[d];
  mu *= (1.f / 16.f);
  var = 0.f;
  #pragma unroll
  for (int d = 0; d < 16; d++) { float dd = h2[d] - mu; var += dd * dd; }
  var *= (1.f / 16.f);
  inv = 1.f / sqrtf(var + 1e-5f);
  float pv = 0.f;
  #pragma unroll
  for (int d = 0; d < 16; d++)
    pv += ((h2[d] - mu) * inv * sg2[d] + sbb2[d]) * swf[d];
  double part = waveReduceSum((double)pv);
  __shared__ double red[4];
  int wid = tid >> 6, lane = tid & 63;
  if (lane == 0) red[wid] = part;
  __syncthreads();
  if (tid == 0) {
    double S = red[0] + red[1] + red[2] + red[3];
    float add = (float)(S / 1280.0);
    if (blockIdx.x % 5 == 0) add += bfc[0];
    atomicAdd(&out[bb], add);
  }
}

// ---------------- launch ------------------------------------------------------
extern "C" void kernel_launch(void* const* d_in, const int* in_sizes, int n_in,
                              void* d_out, int out_size, void* d_ws, size_t ws_size,
                              hipStream_t stream) {
  const float* x    = (const float*)d_in[0];
  const float* cw   = (const float*)d_in[1];
  const float* cb   = (const float*)d_in[2];
  const float* g0   = (const float*)d_in[3];
  const float* bt0  = (const float*)d_in[4];
  const float* wqkv = (const float*)d_in[5];
  const float* bqkv = (const float*)d_in[6];
  const float* wo   = (const float*)d_in[7];
  const float* bo   = (const float*)d_in[8];
  const float* w1   = (const float*)d_in[9];
  const float* b1   = (const float*)d_in[10];
  const float* w2   = (const float*)d_in[11];
  const float* b2   = (const float*)d_in[12];
  const float* g1   = (const float*)d_in[13];
  const float* bb1  = (const float*)d_in[14];
  const float* g2   = (const float*)d_in[15];
  const float* bb2  = (const float*)d_in[16];
  const float* wfc  = (const float*)d_in[17];
  const float* bfc  = (const float*)d_in[18];
  float* out = (float*)d_out;

  float* ws = (float*)d_ws;
  float* xs = ws;                       // 640*2000 = 1,280,000 (filtered in-place;
                                        // dead after k_resample_norm -> reused as A)
  float* y1 = xs + 1280000;             // spacer (dead)
  float* xn = y1 + 1306880;             // 640*1280   =   819,200
  float* x0 = xn + 819200;              // 64*1280*16 = 1,310,720
  float* Q  = x0 + 1310720;
  float* Kb = Q  + 1310720;
  float* Vb = Kb + 1310720;
  float* pe = Vb + 1310720;             // 1280*16 = 20,480  (total ~36 MB)
  float* Abuf = ws;                     // attention output (reuses dead xs)

  FiltArg fc; CorArg co; EigArg eg; FirArg fa;
  build_filt(fc, co);
  build_eig(fc, eg);
  design_fir(fa);

  k_chansel_pe<<<580, 256, 0, stream>>>(x, xs, pe, out);
  k_filtfilt<<<640, 128, 0, stream>>>(xs, fc, co, eg);
  k_resample_norm<<<640, 256, 0, stream>>>(xs, xn, fa);
  k_conv_ln_pe_qkv<<<320, 256, 0, stream>>>(xn, cw, cb, g0, bt0, wqkv, bqkv,
                                            pe, x0, Q, Kb, Vb);
  k_attn_mfma<<<1280, 256, 0, stream>>>(Q, Kb, Vb, Abuf);
  k_combine_pool<<<320, 256, 0, stream>>>(Abuf, x0, wo, bo, w1, b1, w2, b2,
                                          g1, bb1, g2, bb2, wfc, bfc, out);
}

// Round 16
// 235.540 us; speedup vs baseline: 1.2601x; 1.0309x over previous
//
#include <hip/hip_runtime.h>
#include <cmath>
#include <complex>
#include <algorithm>

#ifndef M_PI
#define M_PI 3.14159265358979323846
#endif

typedef _Float16 f16x8 __attribute__((ext_vector_type(8)));
typedef _Float16 f16x4 __attribute__((ext_vector_type(4)));
typedef float f32x4 __attribute__((ext_vector_type(4)));

// ---------------- coefficient structs (passed by value as kernel args) ---------
struct FiltArg {
  double b0[3], b1[3], b2[3], a1[3], a2[3];
  double zi0[3], zi1[3];
};
struct CorArg { double CA[16 * 6]; };  // CA[i][j] = output at step i from unit state e_j
struct EigArg {
  double Pm[36], Pinv[36];   // eigenbasis of the single-step state matrix A
  double czi[6];             // Pinv · (zi vector)
  double lam_re[3], lam_im[3];   // λ_s = p_s^16  (chunk = 16 steps)
  double lami_re[3], lami_im[3]; // λ_s^{-1}
};
struct FirArg { float h[526]; };  // 25 leading zeros + 501-tap kaiser-sinc, *UP

// ---------------- host-side filter design (exact replica of reference) --------
static void design_sos(FiltArg& sa) {
  const int order = 6;
  const double wn = 0.5 / 50.0;
  const double fs = 2.0;
  double warped = 2.0 * fs * std::tan(M_PI * wn / fs);
  std::complex<double> p[6];
  for (int i = 0; i < order; i++) {
    int m = -order + 1 + 2 * i;                      // -5,-3,-1,1,3,5
    p[i] = -std::exp(std::complex<double>(0.0, M_PI * m / (2.0 * order)));
  }
  std::complex<double> prod1(1, 0);
  for (int i = 0; i < 6; i++) prod1 *= -p[i];
  double k = (1.0 / prod1).real();
  for (int i = 0; i < 6; i++) p[i] = warped / p[i];
  const double fs2 = 2.0 * fs;
  std::complex<double> num(1, 0), den(1, 0);
  for (int i = 0; i < 6; i++) { num *= fs2; den *= (fs2 - p[i]); }
  k *= (num / den).real();
  for (int i = 0; i < 6; i++) p[i] = (fs2 + p[i]) / (fs2 - p[i]);
  std::complex<double> pp[3]; int n = 0;
  for (int i = 0; i < 6; i++) if (p[i].imag() > 0) pp[n++] = p[i];
  std::stable_sort(pp, pp + 3,
    [](const std::complex<double>& A, const std::complex<double>& B) {
      return std::fabs(std::abs(A) - 1.0) > std::fabs(std::abs(B) - 1.0);
    });
  double sos[3][6];
  for (int s = 0; s < 3; s++) {
    double g = (s == 0) ? k : 1.0;
    sos[s][0] = g; sos[s][1] = -2.0 * g; sos[s][2] = g;
    sos[s][3] = 1.0; sos[s][4] = -2.0 * pp[s].real(); sos[s][5] = std::norm(pp[s]);
  }
  double scale = 1.0;
  for (int s = 0; s < 3; s++) {
    double b0 = sos[s][0], b1 = sos[s][1], b2 = sos[s][2];
    double a1 = sos[s][4], a2 = sos[s][5];
    double det = 1.0 + a1 + a2;                      // det of [[1+a1,-1],[a2,1]]
    double r0 = b1 - a1 * b0, r1 = b2 - a2 * b0;
    double z0 = (r0 + r1) / det;
    double z1 = ((1.0 + a1) * r1 - a2 * r0) / det;
    sa.b0[s] = b0; sa.b1[s] = b1; sa.b2[s] = b2; sa.a1[s] = a1; sa.a2[s] = a2;
    sa.zi0[s] = scale * z0; sa.zi1[s] = scale * z1;
    scale *= (b0 + b1 + b2) / (1.0 + a1 + a2);
  }
}

static double host_step(const FiltArg& c, double z[6], double v) {
  for (int s = 0; s < 3; s++) {
    double y = c.b0[s] * v + z[2 * s];
    z[2 * s]     = c.b1[s] * v - c.a1[s] * y + z[2 * s + 1];
    z[2 * s + 1] = c.b2[s] * v - c.a2[s] * y;
    v = y;
  }
  return v;
}

static void build_filt(FiltArg& c, CorArg& co) {
  design_sos(c);
  for (int j = 0; j < 6; j++) {
    double z[6] = {0, 0, 0, 0, 0, 0};
    z[j] = 1.0;
    for (int i = 0; i < 16; i++) co.CA[i * 6 + j] = host_step(c, z, 0.0);
  }
}

static void build_eig(const FiltArg& c, EigArg& e) {
  double Pr[36];
  for (int s = 0; s < 3; s++) {
    double a1 = c.a1[s], a2 = c.a2[s];
    std::complex<double> disc = std::sqrt(std::complex<double>(a1 * a1 - 4.0 * a2, 0.0));
    std::complex<double> p = (-a1 + disc) / 2.0;
    if (p.imag() < 0) p = std::conj(p);
    std::complex<double> v[6] = {0, 0, 0, 0, 0, 0};
    v[2 * s] = 1.0;
    v[2 * s + 1] = a1 + p;
    std::complex<double> y = 1.0;
    for (int j = s + 1; j < 3; j++) {
      double b0j = c.b0[j], b1j = c.b1[j], b2j = c.b2[j];
      double a1j = c.a1[j], a2j = c.a2[j];
      std::complex<double> det = p * p + a1j * p + a2j;
      std::complex<double> r0 = (b1j - a1j * b0j) * y;
      std::complex<double> r1 = (b2j - a2j * b0j) * y;
      std::complex<double> z0 = (p * r0 + r1) / det;
      std::complex<double> z1 = ((p + a1j) * r1 - a2j * r0) / det;
      v[2 * j] = z0; v[2 * j + 1] = z1;
      y = b0j * y + z0;
    }
    for (int i = 0; i < 6; i++) {
      Pr[i * 6 + 2 * s]     = v[i].real();
      Pr[i * 6 + 2 * s + 1] = v[i].imag();
    }
    std::complex<double> lam = std::pow(p, 16);
    e.lam_re[s] = lam.real(); e.lam_im[s] = lam.imag();
    std::complex<double> li = 1.0 / lam;
    e.lami_re[s] = li.real(); e.lami_im[s] = li.imag();
  }
  for (int i = 0; i < 36; i++) e.Pm[i] = Pr[i];
  double M[6][12];
  for (int i = 0; i < 6; i++)
    for (int j = 0; j < 6; j++) { M[i][j] = Pr[i * 6 + j]; M[i][6 + j] = (i == j) ? 1.0 : 0.0; }
  for (int col = 0; col < 6; col++) {
    int piv = col;
    for (int i = col + 1; i < 6; i++)
      if (std::fabs(M[i][col]) > std::fabs(M[piv][col])) piv = i;
    if (piv != col) for (int j = 0; j < 12; j++) std::swap(M[col][j], M[piv][j]);
    double d = M[col][col];
    for (int j = 0; j < 12; j++) M[col][j] /= d;
    for (int i = 0; i < 6; i++) if (i != col) {
      double f = M[i][col];
      for (int j = 0; j < 12; j++) M[i][j] -= f * M[col][j];
    }
  }
  for (int i = 0; i < 6; i++)
    for (int j = 0; j < 6; j++) e.Pinv[i * 6 + j] = M[i][6 + j];
  double zv[6];
  for (int s = 0; s < 3; s++) { zv[2 * s] = c.zi0[s]; zv[2 * s + 1] = c.zi1[s]; }
  for (int i = 0; i < 6; i++) {
    double sum = 0.0;
    for (int j = 0; j < 6; j++) sum += e.Pinv[i * 6 + j] * zv[j];
    e.czi[i] = sum;
  }
}

static double bessel_i0(double x) {
  double s = 1.0, t = 1.0;
  for (int k = 1; k < 64; k++) {
    double u = x / (2.0 * k);
    t *= u * u; s += t;
    if (t < 1e-18 * s) break;
  }
  return s;
}

static void design_fir(FirArg& fa) {
  double h[501];
  const double fc = 1.0 / 25.0;
  double denom = bessel_i0(5.0);
  double sum = 0.0;
  for (int nn = 0; nn < 501; nn++) {
    double m = nn - 250.0;
    double xx = fc * m;
    double snc = (nn == 250) ? 1.0 : std::sin(M_PI * xx) / (M_PI * xx);
    double r = (2.0 * nn) / 500.0 - 1.0;
    double w = bessel_i0(5.0 * std::sqrt(std::max(0.0, 1.0 - r * r))) / denom;
    h[nn] = fc * snc * w; sum += h[nn];
  }
  for (int nn = 0; nn < 25; nn++) fa.h[nn] = 0.0f;          // n_pre_pad = 25
  for (int nn = 0; nn < 501; nn++) fa.h[25 + nn] = (float)(h[nn] / sum * 16.0);
}

// ---------------- device helpers ----------------
__device__ inline double waveReduceSum(double v) {
  #pragma unroll
  for (int off = 32; off > 0; off >>= 1) v += __shfl_down(v, off, 64);
  return v;
}

__device__ inline void cpow_int(double br, double bi, int n, double& rr_, double& ri_) {
  double rr = 1.0, ri = 0.0;
  while (n) {
    if (n & 1) { double t = rr * br - ri * bi; ri = rr * bi + ri * br; rr = t; }
    double t2 = br * br - bi * bi; bi = 2.0 * br * bi; br = t2;
    n >>= 1;
  }
  rr_ = rr; ri_ = ri;
}

// ---------------- kernel 1: chansel + demean, PE table, out-zero (merged) -----
__global__ __launch_bounds__(256) void k_chansel_pe(const float* __restrict__ x,
                                                    float* __restrict__ xs,
                                                    float* __restrict__ pe,
                                                    float* __restrict__ out) {
  int gid = blockIdx.x;
  if (gid < 500) {
    int idx = gid * 256 + threadIdx.x;
    int b = idx / 2000, t = idx % 2000;
    const int ch[10] = {126, 125, 48, 112, 67, 93, 10, 61, 39, 108};
    const float* xb = x + (size_t)b * 128 * 2000;
    float v[10]; float s = 0.f;
    #pragma unroll
    for (int c = 0; c < 10; c++) { v[c] = xb[ch[c] * 2000 + t]; s += v[c]; }
    s *= 0.1f;
    #pragma unroll
    for (int c = 0; c < 10; c++) xs[((size_t)b * 10 + c) * 2000 + t] = v[c] - s;
  } else {
    int i = (gid - 500) * 256 + threadIdx.x;    // [0, 20480)
    int t = i >> 4, d = i & 15, j = d >> 1;
    double div = exp(-((double)(2 * j)) * 0.5756462732485114); // ln(10000)/16
    double a = (double)t * div;
    pe[i] = (float)((d & 1) ? cos(a) : sin(a));
    if (gid == 579 && threadIdx.x < 64) out[threadIdx.x] = 0.f;
  }
}

// ---------------- kernel 2: filtfilt, 128 chunks x 16 steps, eigen prefix -----
#define XR(t) xr[(t) + ((t) >> 5)]
#define YF(t) yf[(t) + ((t) >> 5)]
__global__ __launch_bounds__(128) void k_filtfilt(float* __restrict__ xs,
                                                  FiltArg c, CorArg co, EigArg eg) {
  __shared__ float xr[2112];      // extended input seq (padded)
  __shared__ double yf[2112];     // corrected forward output (padded)
  __shared__ double wsum[3][2];   // wave0 inclusive totals per section
  int r = blockIdx.x;
  int gk = threadIdx.x;           // global chunk id 0..127
  int lane = gk & 63;
  int wv = gk >> 6;
  float* x = xs + (size_t)r * 2000;

  float x0f = x[0], xlf = x[1999];
  for (int t = gk; t < 2048; t += 128) {
    float v;
    if (t < 21)        v = 2.f * x0f - x[21 - t];
    else if (t < 2021) v = x[t - 21];
    else if (t < 2042) v = 2.f * xlf - x[4019 - t];
    else               v = 0.f;
    XR(t) = v;
  }
  __syncthreads();

  double b0[3], b1[3], b2[3], a1[3], a2[3];
  #pragma unroll
  for (int s = 0; s < 3; s++) {
    b0[s] = c.b0[s]; b1[s] = c.b1[s]; b2[s] = c.b2[s];
    a1[s] = c.a1[s]; a2[s] = c.a2[s];
  }
  auto step = [&](double* z, double v) -> double {
    #pragma unroll
    for (int s = 0; s < 3; s++) {
      double y = b0[s] * v + z[2 * s];
      z[2 * s]     = b1[s] * v - a1[s] * y + z[2 * s + 1];
      z[2 * s + 1] = b2[s] * v - a2[s] * y;
      v = y;
    }
    return v;
  };

  auto eigscan = [&](double seed, const double* F, double* zst) {
    double G[6];
    #pragma unroll
    for (int i = 0; i < 6; i++) {
      double s = 0.0;
      #pragma unroll
      for (int j = 0; j < 6; j++) s += eg.Pinv[i * 6 + j] * F[j];
      G[i] = s;
    }
    double tre[3], tim[3], sre[3], sim[3];
    #pragma unroll
    for (int s3 = 0; s3 < 3; s3++) {
      double gre = G[2 * s3], gim = -G[2 * s3 + 1];
      double mre, mim;                                  // λ^{-gk}
      cpow_int(eg.lami_re[s3], eg.lami_im[s3], gk, mre, mim);
      tre[s3] = mre * gre - mim * gim;
      tim[s3] = mre * gim + mim * gre;
      double pr = tre[s3], pi = tim[s3];
      #pragma unroll
      for (int off = 1; off < 64; off <<= 1) {
        double ore = __shfl_up(pr, off, 64);
        double oim = __shfl_up(pi, off, 64);
        pr += (lane >= off) ? ore : 0.0;
        pi += (lane >= off) ? oim : 0.0;
      }
      sre[s3] = pr; sim[s3] = pi;
      if (wv == 0 && lane == 63) { wsum[s3][0] = pr; wsum[s3][1] = pi; }
    }
    __syncthreads();
    double coord[6];
    #pragma unroll
    for (int s3 = 0; s3 < 3; s3++) {
      double inc_re = sre[s3] + (wv ? wsum[s3][0] : 0.0);
      double inc_im = sim[s3] + (wv ? wsum[s3][1] : 0.0);
      double Sre = inc_re - tre[s3], Sim = inc_im - tim[s3];
      double c0re = seed * eg.czi[2 * s3];
      double c0im = -seed * eg.czi[2 * s3 + 1];
      double lkre, lkim;
      cpow_int(eg.lam_re[s3], eg.lam_im[s3], gk, lkre, lkim);
      double lm1re = lkre * eg.lami_re[s3] - lkim * eg.lami_im[s3];
      double lm1im = lkre * eg.lami_im[s3] + lkim * eg.lami_re[s3];
      if (gk == 0) { lm1re = 0.0; lm1im = 0.0; }
      double cre = lkre * c0re - lkim * c0im + lm1re * Sre - lm1im * Sim;
      double cim = lkre * c0im + lkim * c0re + lm1re * Sim + lm1im * Sre;
      coord[2 * s3] = cre;
      coord[2 * s3 + 1] = -cim;
    }
    #pragma unroll
    for (int i = 0; i < 6; i++) {
      double s = 0.0;
      #pragma unroll
      for (int j = 0; j < 6; j++) s += eg.Pm[i * 6 + j] * coord[j];
      zst[i] = s;
    }
  };

  int t0 = gk * 16;
  double z[6], yreg[16], zst[6];

  #pragma unroll
  for (int i = 0; i < 6; i++) z[i] = 0.0;
  for (int i = 0; i < 16; i++) yreg[i] = step(z, (double)XR(t0 + i));
  eigscan((double)XR(0), z, zst);
  for (int i = 0; i < 16; i++) {
    double corr = 0.0;
    #pragma unroll
    for (int j = 0; j < 6; j++) corr += co.CA[i * 6 + j] * zst[j];
    YF(t0 + i) = yreg[i] + corr;
  }
  __syncthreads();

  auto rin = [&](int j) -> double { return (j <= 2041) ? YF(2041 - j) : 0.0; };
  double seedB = YF(2041);
  #pragma unroll
  for (int i = 0; i < 6; i++) z[i] = 0.0;
  for (int i = 0; i < 16; i++) yreg[i] = step(z, rin(t0 + i));
  eigscan(seedB, z, zst);
  for (int i = 0; i < 16; i++) {
    int j = t0 + i;
    if (j >= 21 && j <= 2020) {
      double corr = 0.0;
      #pragma unroll
      for (int jj = 0; jj < 6; jj++) corr += co.CA[i * 6 + jj] * zst[jj];
      x[2020 - j] = (float)(yreg[i] + corr);   // reversed + trimmed
    }
  }
}

// ---------------- kernel 3: polyphase resample + tanh + per-row normalize ----
__global__ __launch_bounds__(256) void k_resample_norm(const float* __restrict__ xf,
                                                       float* __restrict__ xn,
                                                       FirArg fa) {
  __shared__ float xl[2000];
  __shared__ float hl[526];
  int r = blockIdx.x;                         // 640 rows
  const float* x = xf + (size_t)r * 2000;
  for (int i = threadIdx.x; i < 2000; i += 256) xl[i] = x[i];
  for (int i = threadIdx.x; i < 526; i += 256) hl[i] = fa.h[i];
  __syncthreads();
  float vals[5];
  #pragma unroll
  for (int kk = 0; kk < 5; kk++) {
    int o = threadIdx.x + kk * 256;           // 1280 outputs per row
    int P = 25 * (o + 11);
    int phase = P & 15;
    float acc = 0.f;
    for (int m = phase; m <= 525; m += 16) {
      int idx = (P - m) >> 4;
      if (idx >= 0 && idx < 2000) acc += hl[m] * xl[idx];
    }
    vals[kk] = tanhf(acc);
  }
  double s = 0.0, ss = 0.0;
  #pragma unroll
  for (int kk = 0; kk < 5; kk++) {
    s += (double)vals[kk]; ss += (double)vals[kk] * (double)vals[kk];
  }
  s = waveReduceSum(s); ss = waveReduceSum(ss);
  __shared__ double red[8];
  int wid = threadIdx.x >> 6, lane = threadIdx.x & 63;
  if (lane == 0) { red[wid] = s; red[4 + wid] = ss; }
  __syncthreads();
  double S = red[0] + red[1] + red[2] + red[3];
  double SS = red[4] + red[5] + red[6] + red[7];
  double mean = S / 1280.0;
  double var = (SS - 1280.0 * mean * mean) / 1279.0;
  double sd = fmax(sqrt(fmax(var, 0.0)), 1e-6);
  float fmean = (float)mean, finv = (float)(1.0 / sd);
  #pragma unroll
  for (int kk = 0; kk < 5; kk++)
    xn[(size_t)r * 1280 + threadIdx.x + kk * 256] = (vals[kk] - fmean) * finv;
}

// ---------------- kernel 4: conv1d + relu + LN + PE + QKV (K,V emitted f16) ---
// K written padded f16 rows Kp[b][t][32] (d 16..31 zero) and V written
// TRANSPOSED f16 Vt_g[b][d][1280] -- the per-tile f32->f16 converts and the
// scalar-u16 LDS transpose in attn (round-15: 6.55M bank-conflict cycles,
// VALU 51%) are paid once here instead of once per consuming block.
__global__ __launch_bounds__(256) void k_conv_ln_pe_qkv(const float* __restrict__ xn,
    const float* __restrict__ cw, const float* __restrict__ cb,
    const float* __restrict__ g0, const float* __restrict__ bt0,
    const float* __restrict__ wqkv, const float* __restrict__ bqkv,
    const float* __restrict__ pe,
    float* __restrict__ x0, float* __restrict__ Q,
    _Float16* __restrict__ Kp, _Float16* __restrict__ Vt_g) {
  __shared__ float w[480], bias[16], gg[16], gb[16];
  __shared__ float wq[768], bq[48];
  for (int i = threadIdx.x; i < 480; i += 256) w[i] = cw[i];
  for (int i = threadIdx.x; i < 768; i += 256) wq[i] = wqkv[i];
  if (threadIdx.x < 16) {
    bias[threadIdx.x] = cb[threadIdx.x];
    gg[threadIdx.x] = g0[threadIdx.x];
    gb[threadIdx.x] = bt0[threadIdx.x];
  }
  if (threadIdx.x < 48) bq[threadIdx.x] = bqkv[threadIdx.x];
  __syncthreads();
  int idx = blockIdx.x * 256 + threadIdx.x;
  int b = idx / 1280, t = idx % 1280;
  const float* xb = xn + (size_t)b * 10 * 1280;
  float in[10][3];
  #pragma unroll
  for (int i = 0; i < 10; i++)
    #pragma unroll
    for (int k = 0; k < 3; k++) {
      int tt = t - 1 + k;
      in[i][k] = (tt >= 0 && tt < 1280) ? xb[i * 1280 + tt] : 0.f;
    }
  float o[16];
  #pragma unroll
  for (int oc = 0; oc < 16; oc++) {
    float a = bias[oc];
    #pragma unroll
    for (int i = 0; i < 10; i++)
      #pragma unroll
      for (int k = 0; k < 3; k++) a += in[i][k] * w[oc * 30 + i * 3 + k];
    o[oc] = fmaxf(a, 0.f);
  }
  float mu = 0.f;
  #pragma unroll
  for (int d = 0; d < 16; d++) mu += o[d];
  mu *= (1.f / 16.f);
  float var = 0.f;
  #pragma unroll
  for (int d = 0; d < 16; d++) { float dd = o[d] - mu; var += dd * dd; }
  var *= (1.f / 16.f);
  float inv = 1.f / sqrtf(var + 1e-5f);
  float xv[16];
  float* outp = x0 + (size_t)idx * 16;
  const float* pep = pe + t * 16;
  #pragma unroll
  for (int d = 0; d < 16; d++) {
    xv[d] = (o[d] - mu) * inv * gg[d] + gb[d] + pep[d];
    outp[d] = xv[d];
  }
  float* qp = Q + (size_t)idx * 16;
  #pragma unroll
  for (int j = 0; j < 16; j++) {
    float a = bq[j];
    #pragma unroll
    for (int d = 0; d < 16; d++) a += xv[d] * wq[j * 16 + d];
    qp[j] = a;
  }
  // K: padded f16 row
  {
    _Float16* kp = Kp + (size_t)idx * 32;
    #pragma unroll
    for (int j = 0; j < 16; j++) {
      float a = bq[16 + j];
      #pragma unroll
      for (int d = 0; d < 16; d++) a += xv[d] * wq[(16 + j) * 16 + d];
      kp[j] = (_Float16)a;
    }
    f16x8 zz;
    #pragma unroll
    for (int j = 0; j < 8; j++) zz[j] = (_Float16)0.f;
    *(f16x8*)&kp[16] = zz;
    *(f16x8*)&kp[24] = zz;
  }
  // V: transposed f16 (coalesced 2B stores across consecutive t)
  {
    _Float16* vt = Vt_g + (size_t)b * 16 * 1280 + t;
    #pragma unroll
    for (int j = 0; j < 16; j++) {
      float a = bq[32 + j];
      #pragma unroll
      for (int d = 0; d < 16; d++) a += xv[d] * wq[(32 + j) * 16 + d];
      vt[j * 1280] = (_Float16)a;
    }
  }
}

// ---------------- kernel 5: MFMA attention (f16 inputs, clean LDS layouts) ----
// Ks2 stride 32 halves: read chunk index = 4*col+quad -> consecutive 16B
// chunks across the wave (provably conflict-free). Vt stride 72 (structural-
// min reads), staged with one f16x8 per thread. Staging has zero converts.
#define ATT_SHIFT 12.0f
__global__ __launch_bounds__(256) void k_attn_mfma(const float* __restrict__ Q,
    const _Float16* __restrict__ Kp, const _Float16* __restrict__ Vt_g,
    float* __restrict__ A) {
  __shared__ __align__(16) _Float16 Ks2[64 * 32];    // [key][d0..31]
  __shared__ __align__(16) _Float16 Vt[16 * 72];     // [d][key]
  __shared__ __align__(16) _Float16 Pld[4][16 * 40]; // per-wave [qrow][key32]
  int tid = threadIdx.x;
  int b  = blockIdx.x / 20;
  int rg = blockIdx.x % 20;
  int wv = tid >> 6;
  int lane = tid & 63;
  int col = lane & 15;
  int quad = lane >> 4;
  size_t base = (size_t)b * 1280;
  int row0 = rg * 64 + wv * 16;

  f16x8 qf;
  #pragma unroll
  for (int j = 0; j < 8; j++) qf[j] = (_Float16)0.f;
  if (quad < 2) {
    const float* qp = Q + (base + row0 + col) * 16 + quad * 8;
    #pragma unroll
    for (int j = 0; j < 8; j++) qf[j] = (_Float16)(0.25f * qp[j]);
  }
  f32x4 oacc = {0.f, 0.f, 0.f, 0.f};
  float lacc = 0.f;

  const _Float16* vt_b = Vt_g + (size_t)b * 16 * 1280;

  for (int s = 0; s < 20; s++) {
    __syncthreads();
    // Ks2: 64 keys x 64B = 4KB = 256 chunks; thread tid copies chunk tid
    *(f16x8*)&Ks2[tid * 8] =
        *(const f16x8*)(Kp + (base + s * 64) * 32 + tid * 8);
    // Vt: 16 d-rows x 64 keys; 128 chunks; threads [0,128)
    if (tid < 128) {
      int d = tid >> 3, qc = tid & 7;
      *(f16x8*)&Vt[d * 72 + qc * 8] =
          *(const f16x8*)(vt_b + d * 1280 + s * 64 + qc * 8);
    }
    __syncthreads();
    #pragma unroll
    for (int c = 0; c < 2; c++) {
      #pragma unroll
      for (int t = 0; t < 2; t++) {
        int keyoff = c * 32 + t * 16;
        f16x8 af = *(f16x8*)&Ks2[(keyoff + col) * 32 + quad * 8];
        f32x4 sf = {0.f, 0.f, 0.f, 0.f};
        sf = __builtin_amdgcn_mfma_f32_16x16x32_f16(af, qf, sf, 0, 0, 0);
        f16x4 ph;
        float psum = 0.f;
        #pragma unroll
        for (int r = 0; r < 4; r++) {
          float p = __expf(sf[r] - ATT_SHIFT);
          psum += p;
          ph[r] = (_Float16)p;
        }
        lacc += psum;
        *(f16x4*)&Pld[wv][col * 40 + t * 16 + quad * 4] = ph;
      }
      __syncthreads();
      f16x8 pf = *(f16x8*)&Pld[wv][col * 40 + quad * 8];
      f16x8 vf = *(f16x8*)&Vt[col * 72 + c * 32 + quad * 8];
      oacc = __builtin_amdgcn_mfma_f32_16x16x32_f16(pf, vf, oacc, 0, 0, 0);
      __syncthreads();
    }
  }
  lacc += __shfl_xor(lacc, 16, 64);
  lacc += __shfl_xor(lacc, 32, 64);
  #pragma unroll
  for (int r = 0; r < 4; r++) {
    float lr = __shfl(lacc, quad * 4 + r, 64);
    A[(base + row0 + quad * 4 + r) * 16 + col] = oacc[r] / lr;
  }
}

// ---------------- kernel 6: combine + wo + LN1 + FFN + LN2 + pool (fused) -----
__global__ __launch_bounds__(256) void k_combine_pool(
    const float* __restrict__ A, const float* __restrict__ x0,
    const float* __restrict__ wo, const float* __restrict__ bo,
    const float* __restrict__ w1, const float* __restrict__ b1,
    const float* __restrict__ w2, const float* __restrict__ b2,
    const float* __restrict__ g1, const float* __restrict__ bb1,
    const float* __restrict__ g2, const float* __restrict__ bb2,
    const float* __restrict__ wfc, const float* __restrict__ bfc,
    float* __restrict__ out) {
  __shared__ float swo[256], sw1[512], sw2[512];
  __shared__ float sbo[16], sb1[32], sb2[16], sg1[16], sbb1[16], sg2[16], sbb2[16];
  __shared__ float swf[16];
  int tid = threadIdx.x;
  swo[tid] = wo[tid];
  for (int i = tid; i < 512; i += 256) { sw1[i] = w1[i]; sw2[i] = w2[i]; }
  if (tid < 16) {
    sbo[tid] = bo[tid]; sb2[tid] = b2[tid];
    sg1[tid] = g1[tid]; sbb1[tid] = bb1[tid];
    sg2[tid] = g2[tid]; sbb2[tid] = bb2[tid];
    swf[tid] = wfc[tid];
  }
  if (tid < 32) sb1[tid] = b1[tid];
  __syncthreads();

  int idx = blockIdx.x * 256 + tid;          // [0, 81920)
  int bb = blockIdx.x / 5;
  const float* pa = A + (size_t)idx * 16;
  float a[16];
  #pragma unroll
  for (int d = 0; d < 16; d++) a[d] = pa[d];
  float h[16];
  const float* xr = x0 + (size_t)idx * 16;
  #pragma unroll
  for (int d = 0; d < 16; d++) {
    float o = sbo[d];
    #pragma unroll
    for (int e = 0; e < 16; e++) o += a[e] * swo[d * 16 + e];
    h[d] = xr[d] + o;
  }
  float mu = 0.f;
  #pragma unroll
  for (int d = 0; d < 16; d++) mu += h[d];
  mu *= (1.f / 16.f);
  float var = 0.f;
  #pragma unroll
  for (int d = 0; d < 16; d++) { float dd = h[d] - mu; var += dd * dd; }
  var *= (1.f / 16.f);
  float inv = 1.f / sqrtf(var + 1e-5f);
  float x1[16];
  #pragma unroll
  for (int d = 0; d < 16; d++) x1[d] = (h[d] - mu) * inv * sg1[d] + sbb1[d];
  float t1[32];
  #pragma unroll
  for (int j = 0; j < 32; j++) {
    float u = sb1[j];
    #pragma unroll
    for (int d = 0; d < 16; d++) u += x1[d] * sw1[j * 16 + d];
    t1[j] = fmaxf(u, 0.f);
  }
  float h2[16];
  #pragma unroll
  for (int d = 0; d < 16; d++) {
    float u = sb2[d];
    #pragma unroll
    for (int j = 0; j < 32; j++) u += t1[j] * sw2[d * 32 + j];
    h2[d] = x1[d] + u;
  }
  mu = 0.f;
  #pragma unroll
  for (int d = 0; d < 16; d++) mu += h2[d];
  mu *= (1.f / 16.f);
  var = 0.f;
  #pragma unroll
  for (int d = 0; d < 16; d++) { float dd = h2[d] - mu; var += dd * dd; }
  var *= (1.f / 16.f);
  inv = 1.f / sqrtf(var + 1e-5f);
  float pv = 0.f;
  #pragma unroll
  for (int d = 0; d < 16; d++)
    pv += ((h2[d] - mu) * inv * sg2[d] + sbb2[d]) * swf[d];
  double part = waveReduceSum((double)pv);
  __shared__ double red[4];
  int wid = tid >> 6, lane = tid & 63;
  if (lane == 0) red[wid] = part;
  __syncthreads();
  if (tid == 0) {
    double S = red[0] + red[1] + red[2] + red[3];
    float add = (float)(S / 1280.0);
    if (blockIdx.x % 5 == 0) add += bfc[0];
    atomicAdd(&out[bb], add);
  }
}

// ---------------- launch ------------------------------------------------------
extern "C" void kernel_launch(void* const* d_in, const int* in_sizes, int n_in,
                              void* d_out, int out_size, void* d_ws, size_t ws_size,
                              hipStream_t stream) {
  const float* x    = (const float*)d_in[0];
  const float* cw   = (const float*)d_in[1];
  const float* cb   = (const float*)d_in[2];
  const float* g0   = (const float*)d_in[3];
  const float* bt0  = (const float*)d_in[4];
  const float* wqkv = (const float*)d_in[5];
  const float* bqkv = (const float*)d_in[6];
  const float* wo   = (const float*)d_in[7];
  const float* bo   = (const float*)d_in[8];
  const float* w1   = (const float*)d_in[9];
  const float* b1   = (const float*)d_in[10];
  const float* w2   = (const float*)d_in[11];
  const float* b2   = (const float*)d_in[12];
  const float* g1   = (const float*)d_in[13];
  const float* bb1  = (const float*)d_in[14];
  const float* g2   = (const float*)d_in[15];
  const float* bb2  = (const float*)d_in[16];
  const float* wfc  = (const float*)d_in[17];
  const float* bfc  = (const float*)d_in[18];
  float* out = (float*)d_out;

  float* ws = (float*)d_ws;
  float* xs = ws;                       // 640*2000 = 1,280,000 (filtered in-place;
                                        // dead after k_resample_norm -> reused as A)
  float* y1 = xs + 1280000;             // spacer (dead)
  float* xn = y1 + 1306880;             // 640*1280   =   819,200
  float* x0 = xn + 819200;              // 64*1280*16 = 1,310,720
  float* Q  = x0 + 1310720;
  _Float16* Kp   = (_Float16*)(Q + 1310720);      // 64*1280*32 f16 = 1,310,720 floats
  _Float16* Vt_g = (_Float16*)(Q + 2621440);      // 64*16*1280 f16 =   655,360 floats
  float* pe = Q + 2621440 + 655360;     // 1280*16 = 20,480  (total ~34 MB)
  float* Abuf = ws;                     // attention output (reuses dead xs)

  FiltArg fc; CorArg co; EigArg eg; FirArg fa;
  build_filt(fc, co);
  build_eig(fc, eg);
  design_fir(fa);

  k_chansel_pe<<<580, 256, 0, stream>>>(x, xs, pe, out);
  k_filtfilt<<<640, 128, 0, stream>>>(xs, fc, co, eg);
  k_resample_norm<<<640, 256, 0, stream>>>(xs, xn, fa);
  k_conv_ln_pe_qkv<<<320, 256, 0, stream>>>(xn, cw, cb, g0, bt0, wqkv, bqkv,
                                            pe, x0, Q, Kp, Vt_g);
  k_attn_mfma<<<1280, 256, 0, stream>>>(Q, Kp, Vt_g, Abuf);
  k_combine_pool<<<320, 256, 0, stream>>>(Abuf, x0, wo, bo, w1, b1, w2, b2,
                                          g1, bb1, g2, bb2, wfc, bfc, out);
}

// Round 17
// 227.745 us; speedup vs baseline: 1.3033x; 1.0342x over previous
//
#include <hip/hip_runtime.h>
#include <cmath>
#include <complex>
#include <algorithm>

#ifndef M_PI
#define M_PI 3.14159265358979323846
#endif

typedef _Float16 f16x8 __attribute__((ext_vector_type(8)));
typedef _Float16 f16x4 __attribute__((ext_vector_type(4)));
typedef float f32x4 __attribute__((ext_vector_type(4)));

// ---------------- coefficient structs (passed by value as kernel args) ---------
struct FiltArg {
  double b0[3], b1[3], b2[3], a1[3], a2[3];
  double zi0[3], zi1[3];
};
struct CorArg { double CA[16 * 6]; };  // CA[i][j] = output at step i from unit state e_j
struct EigArg {
  double Pm[36], Pinv[36];   // eigenbasis of the single-step state matrix A
  double czi[6];             // Pinv · (zi vector)
  double lam_re[3], lam_im[3];   // λ_s = p_s^16  (chunk = 16 steps)
  double lami_re[3], lami_im[3]; // λ_s^{-1}
};
struct FirArg { float h[526]; };  // 25 leading zeros + 501-tap kaiser-sinc, *UP

// ---------------- host-side filter design (exact replica of reference) --------
static void design_sos(FiltArg& sa) {
  const int order = 6;
  const double wn = 0.5 / 50.0;
  const double fs = 2.0;
  double warped = 2.0 * fs * std::tan(M_PI * wn / fs);
  std::complex<double> p[6];
  for (int i = 0; i < order; i++) {
    int m = -order + 1 + 2 * i;                      // -5,-3,-1,1,3,5
    p[i] = -std::exp(std::complex<double>(0.0, M_PI * m / (2.0 * order)));
  }
  std::complex<double> prod1(1, 0);
  for (int i = 0; i < 6; i++) prod1 *= -p[i];
  double k = (1.0 / prod1).real();
  for (int i = 0; i < 6; i++) p[i] = warped / p[i];
  const double fs2 = 2.0 * fs;
  std::complex<double> num(1, 0), den(1, 0);
  for (int i = 0; i < 6; i++) { num *= fs2; den *= (fs2 - p[i]); }
  k *= (num / den).real();
  for (int i = 0; i < 6; i++) p[i] = (fs2 + p[i]) / (fs2 - p[i]);
  std::complex<double> pp[3]; int n = 0;
  for (int i = 0; i < 6; i++) if (p[i].imag() > 0) pp[n++] = p[i];
  std::stable_sort(pp, pp + 3,
    [](const std::complex<double>& A, const std::complex<double>& B) {
      return std::fabs(std::abs(A) - 1.0) > std::fabs(std::abs(B) - 1.0);
    });
  double sos[3][6];
  for (int s = 0; s < 3; s++) {
    double g = (s == 0) ? k : 1.0;
    sos[s][0] = g; sos[s][1] = -2.0 * g; sos[s][2] = g;
    sos[s][3] = 1.0; sos[s][4] = -2.0 * pp[s].real(); sos[s][5] = std::norm(pp[s]);
  }
  double scale = 1.0;
  for (int s = 0; s < 3; s++) {
    double b0 = sos[s][0], b1 = sos[s][1], b2 = sos[s][2];
    double a1 = sos[s][4], a2 = sos[s][5];
    double det = 1.0 + a1 + a2;                      // det of [[1+a1,-1],[a2,1]]
    double r0 = b1 - a1 * b0, r1 = b2 - a2 * b0;
    double z0 = (r0 + r1) / det;
    double z1 = ((1.0 + a1) * r1 - a2 * r0) / det;
    sa.b0[s] = b0; sa.b1[s] = b1; sa.b2[s] = b2; sa.a1[s] = a1; sa.a2[s] = a2;
    sa.zi0[s] = scale * z0; sa.zi1[s] = scale * z1;
    scale *= (b0 + b1 + b2) / (1.0 + a1 + a2);
  }
}

static double host_step(const FiltArg& c, double z[6], double v) {
  for (int s = 0; s < 3; s++) {
    double y = c.b0[s] * v + z[2 * s];
    z[2 * s]     = c.b1[s] * v - c.a1[s] * y + z[2 * s + 1];
    z[2 * s + 1] = c.b2[s] * v - c.a2[s] * y;
    v = y;
  }
  return v;
}

static void build_filt(FiltArg& c, CorArg& co) {
  design_sos(c);
  for (int j = 0; j < 6; j++) {
    double z[6] = {0, 0, 0, 0, 0, 0};
    z[j] = 1.0;
    for (int i = 0; i < 16; i++) co.CA[i * 6 + j] = host_step(c, z, 0.0);
  }
}

static void build_eig(const FiltArg& c, EigArg& e) {
  double Pr[36];
  for (int s = 0; s < 3; s++) {
    double a1 = c.a1[s], a2 = c.a2[s];
    std::complex<double> disc = std::sqrt(std::complex<double>(a1 * a1 - 4.0 * a2, 0.0));
    std::complex<double> p = (-a1 + disc) / 2.0;
    if (p.imag() < 0) p = std::conj(p);
    std::complex<double> v[6] = {0, 0, 0, 0, 0, 0};
    v[2 * s] = 1.0;
    v[2 * s + 1] = a1 + p;
    std::complex<double> y = 1.0;
    for (int j = s + 1; j < 3; j++) {
      double b0j = c.b0[j], b1j = c.b1[j], b2j = c.b2[j];
      double a1j = c.a1[j], a2j = c.a2[j];
      std::complex<double> det = p * p + a1j * p + a2j;
      std::complex<double> r0 = (b1j - a1j * b0j) * y;
      std::complex<double> r1 = (b2j - a2j * b0j) * y;
      std::complex<double> z0 = (p * r0 + r1) / det;
      std::complex<double> z1 = ((p + a1j) * r1 - a2j * r0) / det;
      v[2 * j] = z0; v[2 * j + 1] = z1;
      y = b0j * y + z0;
    }
    for (int i = 0; i < 6; i++) {
      Pr[i * 6 + 2 * s]     = v[i].real();
      Pr[i * 6 + 2 * s + 1] = v[i].imag();
    }
    std::complex<double> lam = std::pow(p, 16);
    e.lam_re[s] = lam.real(); e.lam_im[s] = lam.imag();
    std::complex<double> li = 1.0 / lam;
    e.lami_re[s] = li.real(); e.lami_im[s] = li.imag();
  }
  for (int i = 0; i < 36; i++) e.Pm[i] = Pr[i];
  double M[6][12];
  for (int i = 0; i < 6; i++)
    for (int j = 0; j < 6; j++) { M[i][j] = Pr[i * 6 + j]; M[i][6 + j] = (i == j) ? 1.0 : 0.0; }
  for (int col = 0; col < 6; col++) {
    int piv = col;
    for (int i = col + 1; i < 6; i++)
      if (std::fabs(M[i][col]) > std::fabs(M[piv][col])) piv = i;
    if (piv != col) for (int j = 0; j < 12; j++) std::swap(M[col][j], M[piv][j]);
    double d = M[col][col];
    for (int j = 0; j < 12; j++) M[col][j] /= d;
    for (int i = 0; i < 6; i++) if (i != col) {
      double f = M[i][col];
      for (int j = 0; j < 12; j++) M[i][j] -= f * M[col][j];
    }
  }
  for (int i = 0; i < 6; i++)
    for (int j = 0; j < 6; j++) e.Pinv[i * 6 + j] = M[i][6 + j];
  double zv[6];
  for (int s = 0; s < 3; s++) { zv[2 * s] = c.zi0[s]; zv[2 * s + 1] = c.zi1[s]; }
  for (int i = 0; i < 6; i++) {
    double sum = 0.0;
    for (int j = 0; j < 6; j++) sum += e.Pinv[i * 6 + j] * zv[j];
    e.czi[i] = sum;
  }
}

static double bessel_i0(double x) {
  double s = 1.0, t = 1.0;
  for (int k = 1; k < 64; k++) {
    double u = x / (2.0 * k);
    t *= u * u; s += t;
    if (t < 1e-18 * s) break;
  }
  return s;
}

static void design_fir(FirArg& fa) {
  double h[501];
  const double fc = 1.0 / 25.0;
  double denom = bessel_i0(5.0);
  double sum = 0.0;
  for (int nn = 0; nn < 501; nn++) {
    double m = nn - 250.0;
    double xx = fc * m;
    double snc = (nn == 250) ? 1.0 : std::sin(M_PI * xx) / (M_PI * xx);
    double r = (2.0 * nn) / 500.0 - 1.0;
    double w = bessel_i0(5.0 * std::sqrt(std::max(0.0, 1.0 - r * r))) / denom;
    h[nn] = fc * snc * w; sum += h[nn];
  }
  for (int nn = 0; nn < 25; nn++) fa.h[nn] = 0.0f;          // n_pre_pad = 25
  for (int nn = 0; nn < 501; nn++) fa.h[25 + nn] = (float)(h[nn] / sum * 16.0);
}

// ---------------- device helpers ----------------
__device__ inline double waveReduceSum(double v) {
  #pragma unroll
  for (int off = 32; off > 0; off >>= 1) v += __shfl_down(v, off, 64);
  return v;
}

__device__ inline void cpow_int(double br, double bi, int n, double& rr_, double& ri_) {
  double rr = 1.0, ri = 0.0;
  while (n) {
    if (n & 1) { double t = rr * br - ri * bi; ri = rr * bi + ri * br; rr = t; }
    double t2 = br * br - bi * bi; bi = 2.0 * br * bi; br = t2;
    n >>= 1;
  }
  rr_ = rr; ri_ = ri;
}

// ---------------- kernel 1: chansel + demean, PE table, out-zero (merged) -----
__global__ __launch_bounds__(256) void k_chansel_pe(const float* __restrict__ x,
                                                    float* __restrict__ xs,
                                                    float* __restrict__ pe,
                                                    float* __restrict__ out) {
  int gid = blockIdx.x;
  if (gid < 500) {
    int idx = gid * 256 + threadIdx.x;
    int b = idx / 2000, t = idx % 2000;
    const int ch[10] = {126, 125, 48, 112, 67, 93, 10, 61, 39, 108};
    const float* xb = x + (size_t)b * 128 * 2000;
    float v[10]; float s = 0.f;
    #pragma unroll
    for (int c = 0; c < 10; c++) { v[c] = xb[ch[c] * 2000 + t]; s += v[c]; }
    s *= 0.1f;
    #pragma unroll
    for (int c = 0; c < 10; c++) xs[((size_t)b * 10 + c) * 2000 + t] = v[c] - s;
  } else {
    int i = (gid - 500) * 256 + threadIdx.x;    // [0, 20480)
    int t = i >> 4, d = i & 15, j = d >> 1;
    double div = exp(-((double)(2 * j)) * 0.5756462732485114); // ln(10000)/16
    double a = (double)t * div;
    pe[i] = (float)((d & 1) ? cos(a) : sin(a));
    if (gid == 579 && threadIdx.x < 64) out[threadIdx.x] = 0.f;
  }
}

// ---------------- kernel 2: filtfilt, 128 chunks x 16 steps, eigen prefix -----
#define XR(t) xr[(t) + ((t) >> 5)]
#define YF(t) yf[(t) + ((t) >> 5)]
__global__ __launch_bounds__(128) void k_filtfilt(float* __restrict__ xs,
                                                  FiltArg c, CorArg co, EigArg eg) {
  __shared__ float xr[2112];      // extended input seq (padded)
  __shared__ double yf[2112];     // corrected forward output (padded)
  __shared__ double wsum[3][2];   // wave0 inclusive totals per section
  int r = blockIdx.x;
  int gk = threadIdx.x;           // global chunk id 0..127
  int lane = gk & 63;
  int wv = gk >> 6;
  float* x = xs + (size_t)r * 2000;

  float x0f = x[0], xlf = x[1999];
  for (int t = gk; t < 2048; t += 128) {
    float v;
    if (t < 21)        v = 2.f * x0f - x[21 - t];
    else if (t < 2021) v = x[t - 21];
    else if (t < 2042) v = 2.f * xlf - x[4019 - t];
    else               v = 0.f;
    XR(t) = v;
  }
  __syncthreads();

  double b0[3], b1[3], b2[3], a1[3], a2[3];
  #pragma unroll
  for (int s = 0; s < 3; s++) {
    b0[s] = c.b0[s]; b1[s] = c.b1[s]; b2[s] = c.b2[s];
    a1[s] = c.a1[s]; a2[s] = c.a2[s];
  }
  auto step = [&](double* z, double v) -> double {
    #pragma unroll
    for (int s = 0; s < 3; s++) {
      double y = b0[s] * v + z[2 * s];
      z[2 * s]     = b1[s] * v - a1[s] * y + z[2 * s + 1];
      z[2 * s + 1] = b2[s] * v - a2[s] * y;
      v = y;
    }
    return v;
  };

  auto eigscan = [&](double seed, const double* F, double* zst) {
    double G[6];
    #pragma unroll
    for (int i = 0; i < 6; i++) {
      double s = 0.0;
      #pragma unroll
      for (int j = 0; j < 6; j++) s += eg.Pinv[i * 6 + j] * F[j];
      G[i] = s;
    }
    double tre[3], tim[3], sre[3], sim[3];
    #pragma unroll
    for (int s3 = 0; s3 < 3; s3++) {
      double gre = G[2 * s3], gim = -G[2 * s3 + 1];
      double mre, mim;                                  // λ^{-gk}
      cpow_int(eg.lami_re[s3], eg.lami_im[s3], gk, mre, mim);
      tre[s3] = mre * gre - mim * gim;
      tim[s3] = mre * gim + mim * gre;
      double pr = tre[s3], pi = tim[s3];
      #pragma unroll
      for (int off = 1; off < 64; off <<= 1) {
        double ore = __shfl_up(pr, off, 64);
        double oim = __shfl_up(pi, off, 64);
        pr += (lane >= off) ? ore : 0.0;
        pi += (lane >= off) ? oim : 0.0;
      }
      sre[s3] = pr; sim[s3] = pi;
      if (wv == 0 && lane == 63) { wsum[s3][0] = pr; wsum[s3][1] = pi; }
    }
    __syncthreads();
    double coord[6];
    #pragma unroll
    for (int s3 = 0; s3 < 3; s3++) {
      double inc_re = sre[s3] + (wv ? wsum[s3][0] : 0.0);
      double inc_im = sim[s3] + (wv ? wsum[s3][1] : 0.0);
      double Sre = inc_re - tre[s3], Sim = inc_im - tim[s3];
      double c0re = seed * eg.czi[2 * s3];
      double c0im = -seed * eg.czi[2 * s3 + 1];
      double lkre, lkim;
      cpow_int(eg.lam_re[s3], eg.lam_im[s3], gk, lkre, lkim);
      double lm1re = lkre * eg.lami_re[s3] - lkim * eg.lami_im[s3];
      double lm1im = lkre * eg.lami_im[s3] + lkim * eg.lami_re[s3];
      if (gk == 0) { lm1re = 0.0; lm1im = 0.0; }
      double cre = lkre * c0re - lkim * c0im + lm1re * Sre - lm1im * Sim;
      double cim = lkre * c0im + lkim * c0re + lm1re * Sim + lm1im * Sre;
      coord[2 * s3] = cre;
      coord[2 * s3 + 1] = -cim;
    }
    #pragma unroll
    for (int i = 0; i < 6; i++) {
      double s = 0.0;
      #pragma unroll
      for (int j = 0; j < 6; j++) s += eg.Pm[i * 6 + j] * coord[j];
      zst[i] = s;
    }
  };

  int t0 = gk * 16;
  double z[6], yreg[16], zst[6];

  #pragma unroll
  for (int i = 0; i < 6; i++) z[i] = 0.0;
  for (int i = 0; i < 16; i++) yreg[i] = step(z, (double)XR(t0 + i));
  eigscan((double)XR(0), z, zst);
  for (int i = 0; i < 16; i++) {
    double corr = 0.0;
    #pragma unroll
    for (int j = 0; j < 6; j++) corr += co.CA[i * 6 + j] * zst[j];
    YF(t0 + i) = yreg[i] + corr;
  }
  __syncthreads();

  auto rin = [&](int j) -> double { return (j <= 2041) ? YF(2041 - j) : 0.0; };
  double seedB = YF(2041);
  #pragma unroll
  for (int i = 0; i < 6; i++) z[i] = 0.0;
  for (int i = 0; i < 16; i++) yreg[i] = step(z, rin(t0 + i));
  eigscan(seedB, z, zst);
  for (int i = 0; i < 16; i++) {
    int j = t0 + i;
    if (j >= 21 && j <= 2020) {
      double corr = 0.0;
      #pragma unroll
      for (int jj = 0; jj < 6; jj++) corr += co.CA[i * 6 + jj] * zst[jj];
      x[2020 - j] = (float)(yreg[i] + corr);   // reversed + trimmed
    }
  }
}

// ---------------- kernel 3: polyphase resample + tanh + per-row normalize ----
__global__ __launch_bounds__(256) void k_resample_norm(const float* __restrict__ xf,
                                                       float* __restrict__ xn,
                                                       FirArg fa) {
  __shared__ float xl[2000];
  __shared__ float hl[526];
  int r = blockIdx.x;                         // 640 rows
  const float* x = xf + (size_t)r * 2000;
  for (int i = threadIdx.x; i < 2000; i += 256) xl[i] = x[i];
  for (int i = threadIdx.x; i < 526; i += 256) hl[i] = fa.h[i];
  __syncthreads();
  float vals[5];
  #pragma unroll
  for (int kk = 0; kk < 5; kk++) {
    int o = threadIdx.x + kk * 256;           // 1280 outputs per row
    int P = 25 * (o + 11);
    int phase = P & 15;
    float acc = 0.f;
    for (int m = phase; m <= 525; m += 16) {
      int idx = (P - m) >> 4;
      if (idx >= 0 && idx < 2000) acc += hl[m] * xl[idx];
    }
    vals[kk] = tanhf(acc);
  }
  double s = 0.0, ss = 0.0;
  #pragma unroll
  for (int kk = 0; kk < 5; kk++) {
    s += (double)vals[kk]; ss += (double)vals[kk] * (double)vals[kk];
  }
  s = waveReduceSum(s); ss = waveReduceSum(ss);
  __shared__ double red[8];
  int wid = threadIdx.x >> 6, lane = threadIdx.x & 63;
  if (lane == 0) { red[wid] = s; red[4 + wid] = ss; }
  __syncthreads();
  double S = red[0] + red[1] + red[2] + red[3];
  double SS = red[4] + red[5] + red[6] + red[7];
  double mean = S / 1280.0;
  double var = (SS - 1280.0 * mean * mean) / 1279.0;
  double sd = fmax(sqrt(fmax(var, 0.0)), 1e-6);
  float fmean = (float)mean, finv = (float)(1.0 / sd);
  #pragma unroll
  for (int kk = 0; kk < 5; kk++)
    xn[(size_t)r * 1280 + threadIdx.x + kk * 256] = (vals[kk] - fmean) * finv;
}

// ---------------- kernel 4: conv1d + relu + LN + PE + QKV (K,V emitted f16) ---
__global__ __launch_bounds__(256) void k_conv_ln_pe_qkv(const float* __restrict__ xn,
    const float* __restrict__ cw, const float* __restrict__ cb,
    const float* __restrict__ g0, const float* __restrict__ bt0,
    const float* __restrict__ wqkv, const float* __restrict__ bqkv,
    const float* __restrict__ pe,
    float* __restrict__ x0, float* __restrict__ Q,
    _Float16* __restrict__ Kp, _Float16* __restrict__ Vt_g) {
  __shared__ float w[480], bias[16], gg[16], gb[16];
  __shared__ float wq[768], bq[48];
  for (int i = threadIdx.x; i < 480; i += 256) w[i] = cw[i];
  for (int i = threadIdx.x; i < 768; i += 256) wq[i] = wqkv[i];
  if (threadIdx.x < 16) {
    bias[threadIdx.x] = cb[threadIdx.x];
    gg[threadIdx.x] = g0[threadIdx.x];
    gb[threadIdx.x] = bt0[threadIdx.x];
  }
  if (threadIdx.x < 48) bq[threadIdx.x] = bqkv[threadIdx.x];
  __syncthreads();
  int idx = blockIdx.x * 256 + threadIdx.x;
  int b = idx / 1280, t = idx % 1280;
  const float* xb = xn + (size_t)b * 10 * 1280;
  float in[10][3];
  #pragma unroll
  for (int i = 0; i < 10; i++)
    #pragma unroll
    for (int k = 0; k < 3; k++) {
      int tt = t - 1 + k;
      in[i][k] = (tt >= 0 && tt < 1280) ? xb[i * 1280 + tt] : 0.f;
    }
  float o[16];
  #pragma unroll
  for (int oc = 0; oc < 16; oc++) {
    float a = bias[oc];
    #pragma unroll
    for (int i = 0; i < 10; i++)
      #pragma unroll
      for (int k = 0; k < 3; k++) a += in[i][k] * w[oc * 30 + i * 3 + k];
    o[oc] = fmaxf(a, 0.f);
  }
  float mu = 0.f;
  #pragma unroll
  for (int d = 0; d < 16; d++) mu += o[d];
  mu *= (1.f / 16.f);
  float var = 0.f;
  #pragma unroll
  for (int d = 0; d < 16; d++) { float dd = o[d] - mu; var += dd * dd; }
  var *= (1.f / 16.f);
  float inv = 1.f / sqrtf(var + 1e-5f);
  float xv[16];
  float* outp = x0 + (size_t)idx * 16;
  const float* pep = pe + t * 16;
  #pragma unroll
  for (int d = 0; d < 16; d++) {
    xv[d] = (o[d] - mu) * inv * gg[d] + gb[d] + pep[d];
    outp[d] = xv[d];
  }
  float* qp = Q + (size_t)idx * 16;
  #pragma unroll
  for (int j = 0; j < 16; j++) {
    float a = bq[j];
    #pragma unroll
    for (int d = 0; d < 16; d++) a += xv[d] * wq[j * 16 + d];
    qp[j] = a;
  }
  {
    _Float16* kp = Kp + (size_t)idx * 32;
    #pragma unroll
    for (int j = 0; j < 16; j++) {
      float a = bq[16 + j];
      #pragma unroll
      for (int d = 0; d < 16; d++) a += xv[d] * wq[(16 + j) * 16 + d];
      kp[j] = (_Float16)a;
    }
    f16x8 zz;
    #pragma unroll
    for (int j = 0; j < 8; j++) zz[j] = (_Float16)0.f;
    *(f16x8*)&kp[16] = zz;
    *(f16x8*)&kp[24] = zz;
  }
  {
    _Float16* vt = Vt_g + (size_t)b * 16 * 1280 + t;
    #pragma unroll
    for (int j = 0; j < 16; j++) {
      float a = bq[32 + j];
      #pragma unroll
      for (int d = 0; d < 16; d++) a += xv[d] * wq[(32 + j) * 16 + d];
      vt[j * 1280] = (_Float16)a;
    }
  }
}

// ---------------- kernel 5: MFMA attention + combine + pool (fused) -----------
// After the key loop, waves park normalized output rows in Aly[64][17] LDS;
// wave 0 (64 threads = the block's 64 rows) runs wo+LN1+FFN+LN2+pool and
// lane 0 atomically accumulates out[b]. Removes the combine dispatch and the
// 2x5.2MB A round-trip.
#define ATT_SHIFT 12.0f
__global__ __launch_bounds__(256) void k_attn_combine(const float* __restrict__ Q,
    const _Float16* __restrict__ Kp, const _Float16* __restrict__ Vt_g,
    const float* __restrict__ x0,
    const float* __restrict__ wo, const float* __restrict__ bo,
    const float* __restrict__ w1, const float* __restrict__ b1,
    const float* __restrict__ w2, const float* __restrict__ b2,
    const float* __restrict__ g1, const float* __restrict__ bb1,
    const float* __restrict__ g2, const float* __restrict__ bb2,
    const float* __restrict__ wfc, const float* __restrict__ bfc,
    float* __restrict__ out) {
  __shared__ __align__(16) _Float16 Ks2[64 * 32];    // [key][d0..31]
  __shared__ __align__(16) _Float16 Vt[16 * 72];     // [d][key]
  __shared__ __align__(16) _Float16 Pld[4][16 * 40]; // per-wave [qrow][key32]
  __shared__ float Aly[64][17];                      // attn out rows (padded)
  __shared__ float swo[256], sw1[512], sw2[512];
  __shared__ float sbo[16], sb1[32], sb2[16], sg1[16], sbb1[16], sg2[16], sbb2[16];
  __shared__ float swf[16];
  int tid = threadIdx.x;
  int b  = blockIdx.x / 20;
  int rg = blockIdx.x % 20;
  int wv = tid >> 6;
  int lane = tid & 63;
  int col = lane & 15;
  int quad = lane >> 4;
  size_t base = (size_t)b * 1280;
  int row0 = rg * 64 + wv * 16;

  // stage combine weights (overlaps first tile staging)
  swo[tid] = wo[tid];
  for (int i = tid; i < 512; i += 256) { sw1[i] = w1[i]; sw2[i] = w2[i]; }
  if (tid < 16) {
    sbo[tid] = bo[tid]; sb2[tid] = b2[tid];
    sg1[tid] = g1[tid]; sbb1[tid] = bb1[tid];
    sg2[tid] = g2[tid]; sbb2[tid] = bb2[tid];
    swf[tid] = wfc[tid];
  }
  if (tid < 32) sb1[tid] = b1[tid];

  f16x8 qf;
  #pragma unroll
  for (int j = 0; j < 8; j++) qf[j] = (_Float16)0.f;
  if (quad < 2) {
    const float* qp = Q + (base + row0 + col) * 16 + quad * 8;
    #pragma unroll
    for (int j = 0; j < 8; j++) qf[j] = (_Float16)(0.25f * qp[j]);
  }
  f32x4 oacc = {0.f, 0.f, 0.f, 0.f};
  float lacc = 0.f;

  const _Float16* vt_b = Vt_g + (size_t)b * 16 * 1280;

  for (int s = 0; s < 20; s++) {
    __syncthreads();
    *(f16x8*)&Ks2[tid * 8] =
        *(const f16x8*)(Kp + (base + s * 64) * 32 + tid * 8);
    if (tid < 128) {
      int d = tid >> 3, qc = tid & 7;
      *(f16x8*)&Vt[d * 72 + qc * 8] =
          *(const f16x8*)(vt_b + d * 1280 + s * 64 + qc * 8);
    }
    __syncthreads();
    #pragma unroll
    for (int c = 0; c < 2; c++) {
      #pragma unroll
      for (int t = 0; t < 2; t++) {
        int keyoff = c * 32 + t * 16;
        f16x8 af = *(f16x8*)&Ks2[(keyoff + col) * 32 + quad * 8];
        f32x4 sf = {0.f, 0.f, 0.f, 0.f};
        sf = __builtin_amdgcn_mfma_f32_16x16x32_f16(af, qf, sf, 0, 0, 0);
        f16x4 ph;
        float psum = 0.f;
        #pragma unroll
        for (int r = 0; r < 4; r++) {
          float p = __expf(sf[r] - ATT_SHIFT);
          psum += p;
          ph[r] = (_Float16)p;
        }
        lacc += psum;
        *(f16x4*)&Pld[wv][col * 40 + t * 16 + quad * 4] = ph;
      }
      __syncthreads();
      f16x8 pf = *(f16x8*)&Pld[wv][col * 40 + quad * 8];
      f16x8 vf = *(f16x8*)&Vt[col * 72 + c * 32 + quad * 8];
      oacc = __builtin_amdgcn_mfma_f32_16x16x32_f16(pf, vf, oacc, 0, 0, 0);
      __syncthreads();
    }
  }
  lacc += __shfl_xor(lacc, 16, 64);
  lacc += __shfl_xor(lacc, 32, 64);
  #pragma unroll
  for (int r = 0; r < 4; r++) {
    float lr = __shfl(lacc, quad * 4 + r, 64);
    Aly[wv * 16 + quad * 4 + r][col] = oacc[r] / lr;
  }
  __syncthreads();

  // ---- epilogue: wave 0, one thread per row ----
  if (tid < 64) {
    int grow = rg * 64 + tid;                 // row within batch
    size_t goff = (base + grow) * 16;
    float a[16];
    #pragma unroll
    for (int d = 0; d < 16; d++) a[d] = Aly[tid][d];
    float h[16];
    const float* xr = x0 + goff;
    #pragma unroll
    for (int d = 0; d < 16; d++) {
      float o = sbo[d];
      #pragma unroll
      for (int e = 0; e < 16; e++) o += a[e] * swo[d * 16 + e];
      h[d] = xr[d] + o;
    }
    float mu = 0.f;
    #pragma unroll
    for (int d = 0; d < 16; d++) mu += h[d];
    mu *= (1.f / 16.f);
    float var = 0.f;
    #pragma unroll
    for (int d = 0; d < 16; d++) { float dd = h[d] - mu; var += dd * dd; }
    var *= (1.f / 16.f);
    float inv = 1.f / sqrtf(var + 1e-5f);
    float x1[16];
    #pragma unroll
    for (int d = 0; d < 16; d++) x1[d] = (h[d] - mu) * inv * sg1[d] + sbb1[d];
    float t1[32];
    #pragma unroll
    for (int j = 0; j < 32; j++) {
      float u = sb1[j];
      #pragma unroll
      for (int d = 0; d < 16; d++) u += x1[d] * sw1[j * 16 + d];
      t1[j] = fmaxf(u, 0.f);
    }
    float h2[16];
    #pragma unroll
    for (int d = 0; d < 16; d++) {
      float u = sb2[d];
      #pragma unroll
      for (int j = 0; j < 32; j++) u += t1[j] * sw2[d * 32 + j];
      h2[d] = x1[d] + u;
    }
    mu = 0.f;
    #pragma unroll
    for (int d = 0; d < 16; d++) mu += h2[d];
    mu *= (1.f / 16.f);
    var = 0.f;
    #pragma unroll
    for (int d = 0; d < 16; d++) { float dd = h2[d] - mu; var += dd * dd; }
    var *= (1.f / 16.f);
    inv = 1.f / sqrtf(var + 1e-5f);
    float pv = 0.f;
    #pragma unroll
    for (int d = 0; d < 16; d++)
      pv += ((h2[d] - mu) * inv * sg2[d] + sbb2[d]) * swf[d];
    double part = waveReduceSum((double)pv);
    if (tid == 0) {
      float add = (float)(part / 1280.0);
      if (blockIdx.x % 20 == 0) add += bfc[0];
      atomicAdd(&out[b], add);
    }
  }
}

// ---------------- launch ------------------------------------------------------
extern "C" void kernel_launch(void* const* d_in, const int* in_sizes, int n_in,
                              void* d_out, int out_size, void* d_ws, size_t ws_size,
                              hipStream_t stream) {
  const float* x    = (const float*)d_in[0];
  const float* cw   = (const float*)d_in[1];
  const float* cb   = (const float*)d_in[2];
  const float* g0   = (const float*)d_in[3];
  const float* bt0  = (const float*)d_in[4];
  const float* wqkv = (const float*)d_in[5];
  const float* bqkv = (const float*)d_in[6];
  const float* wo   = (const float*)d_in[7];
  const float* bo   = (const float*)d_in[8];
  const float* w1   = (const float*)d_in[9];
  const float* b1   = (const float*)d_in[10];
  const float* w2   = (const float*)d_in[11];
  const float* b2   = (const float*)d_in[12];
  const float* g1   = (const float*)d_in[13];
  const float* bb1  = (const float*)d_in[14];
  const float* g2   = (const float*)d_in[15];
  const float* bb2  = (const float*)d_in[16];
  const float* wfc  = (const float*)d_in[17];
  const float* bfc  = (const float*)d_in[18];
  float* out = (float*)d_out;

  float* ws = (float*)d_ws;
  float* xs = ws;                       // 640*2000 = 1,280,000 (filtered in-place)
  float* y1 = xs + 1280000;             // spacer (dead)
  float* xn = y1 + 1306880;             // 640*1280   =   819,200
  float* x0 = xn + 819200;              // 64*1280*16 = 1,310,720
  float* Q  = x0 + 1310720;
  _Float16* Kp   = (_Float16*)(Q + 1310720);      // 64*1280*32 f16 = 1,310,720 floats
  _Float16* Vt_g = (_Float16*)(Q + 2621440);      // 64*16*1280 f16 =   655,360 floats
  float* pe = Q + 2621440 + 655360;     // 1280*16 = 20,480  (total ~34 MB)

  FiltArg fc; CorArg co; EigArg eg; FirArg fa;
  build_filt(fc, co);
  build_eig(fc, eg);
  design_fir(fa);

  k_chansel_pe<<<580, 256, 0, stream>>>(x, xs, pe, out);
  k_filtfilt<<<640, 128, 0, stream>>>(xs, fc, co, eg);
  k_resample_norm<<<640, 256, 0, stream>>>(xs, xn, fa);
  k_conv_ln_pe_qkv<<<320, 256, 0, stream>>>(xn, cw, cb, g0, bt0, wqkv, bqkv,
                                            pe, x0, Q, Kp, Vt_g);
  k_attn_combine<<<1280, 256, 0, stream>>>(Q, Kp, Vt_g, x0, wo, bo, w1, b1,
                                           w2, b2, g1, bb1, g2, bb2, wfc, bfc,
                                           out);
}